// Round 5
// baseline (196.721 us; speedup 1.0000x reference)
//
#include <hip/hip_runtime.h>

// Fused causal self-attention block, MI355X gfx950.
// B=2, T=2048, E=1024, H=16, D=64.  All MFMA in bf16 (mfma_f32_16x16x32_bf16),
// fp32 accumulation. Verified fragment layouts (learn_hip m89/m91):
//   A[m = lane&15][k = (lane>>4)*8 + j]   (8 bf16 = 16B contiguous)
//   B[k = (lane>>4)*8 + j][n = lane&15]
//   C/D[row = (lane>>4)*4 + r][col = lane&15]
// R11: GEMM core double-buffered, 1 barrier/K-step, XOR-swizzled LDS.
// R12 FAILED: per-lane global K/V frag loads = L1 transaction-bound. Keep
//   global_load_lds staging. Verified: XOR-swizzled P (conflicts 2.1M->0).
// R13/14: swizzled P + native-cast f2b landed: attn ~41us, total 173.4.
// R15 (this round): k_attn counters showed LDS-PIPE-BOUND (2155 cyc/iter
//   observed ~= 2368 modeled LDS cycles; MFMA 308, VALU 560 per SIMD).
//   Restructure: 4 q-tiles per wave (rows +0/512/1024/1536) halves K/V frag
//   reads per cell (148 -> 100 LDS cyc); 1-wave blocks (64 thr, 1024 blocks,
//   4/CU) -> ZERO barriers; counted s_waitcnt vmcnt(16) keeps next-tile
//   staging in flight (T4); P 4KB pair-reused (per-wave in-order DS + lgkm
//   fence + sched_barrier, rule #18). LDS 36KB/block.

typedef unsigned short u16;
typedef __bf16 bf8 __attribute__((ext_vector_type(8)));
typedef float f32x4 __attribute__((ext_vector_type(4)));

struct __align__(8) u16x4s { u16 v[4]; };

__device__ __forceinline__ u16 f2b(float f) {
    return __builtin_bit_cast(u16, (__bf16)f);         // v_cvt_pk_bf16_f32, RNE
}

__device__ __forceinline__ f32x4 mfma16(bf8 a, bf8 b, f32x4 c) {
    return __builtin_amdgcn_mfma_f32_16x16x32_bf16(a, b, c, 0, 0, 0);
}

__device__ __forceinline__ float fexp2(float x) {
    return __builtin_amdgcn_exp2f(x);                  // v_exp_f32
}

// async global->LDS, 16B per lane. LDS dest must be wave-uniform base + lane*16.
__device__ __forceinline__ void gload_lds16(const u16* g, u16* l) {
    __builtin_amdgcn_global_load_lds(
        (__attribute__((address_space(1))) void*)(g),
        (__attribute__((address_space(3))) void*)(l), 16, 0, 0);
}

// ---------------- prep: x->bf16 convert + both weight transposes ----------------
// blocks [0,4096): cvt; [4096,4864): W_attn tr (16x48); [4864,5120): W_proj tr.
__global__ __launch_bounds__(256) void k_prep(const float* __restrict__ x,
                                              const float* __restrict__ Wa,
                                              const float* __restrict__ Wp,
                                              u16* __restrict__ Xb,
                                              u16* __restrict__ WtA,
                                              u16* __restrict__ WtP) {
    __shared__ float tile[64][65];
    int id = blockIdx.x, t = threadIdx.x;
    if (id < 4096) {                         // convert 4 floats/thread
        int i = id * 256 + t;
        float4 v = ((const float4*)x)[i];
        ushort4 o;
        o.x = f2b(v.x); o.y = f2b(v.y); o.z = f2b(v.z); o.w = f2b(v.w);
        ((ushort4*)Xb)[i] = o;
        return;
    }
    const float* in; u16* out; int N, j;
    if (id < 4864) { j = id - 4096; in = Wa; out = WtA; N = 3072; }
    else           { j = id - 4864; in = Wp; out = WtP; N = 1024; }
    int k0 = (j & 15) * 64, n0 = (j >> 4) * 64;
    int c = t & 63, r0 = t >> 6;
#pragma unroll
    for (int i = 0; i < 16; ++i) {
        int r = r0 + i * 4;
        tile[r][c] = in[(size_t)(k0 + r) * N + n0 + c];
    }
    __syncthreads();
#pragma unroll
    for (int i = 0; i < 16; ++i) {
        int r = r0 + i * 4;
        out[(size_t)(n0 + r) * 1024 + k0 + c] = f2b(tile[c][r]);
    }
}

// =====================================================================
// GEMM core v2: C[128x128]/block, A[M][1024] @ Wt[N][1024]^T.
// Double-buffered XOR-swizzled LDS, 1 barrier per K-step (32 steps).
// =====================================================================
#define GEMM_STAGE(GA0, GA1, GB0, GB1, K, B)                                   \
    do {                                                                       \
        gload_lds16(GA0 + (K), As[B] + tid * 8);                               \
        gload_lds16(GA1 + (K), As[B] + (256 + tid) * 8);                       \
        gload_lds16(GB0 + (K), Bs[B] + tid * 8);                               \
        gload_lds16(GB1 + (K), Bs[B] + (256 + tid) * 8);                       \
    } while (0)

#define GEMM_CORE(Aptr, Bptr)                                                  \
    int tid = threadIdx.x;                                                     \
    int w = tid >> 6, lane = tid & 63, l16 = lane & 15, quad = lane >> 4;      \
    int m0 = blockIdx.x * 128, n0 = blockIdx.y * 128;                          \
    int wr = (w >> 1) * 64, wc = (w & 1) * 64;                                 \
    __shared__ u16 As[2][128 * 32];                                            \
    __shared__ u16 Bs[2][128 * 32];                                            \
    f32x4 acc[4][4];                                                           \
    _Pragma("unroll") for (int mi = 0; mi < 4; ++mi)                           \
        _Pragma("unroll") for (int ni = 0; ni < 4; ++ni)                       \
            _Pragma("unroll") for (int r = 0; r < 4; ++r) acc[mi][ni][r] = 0.f;\
    int srow0 = tid >> 2, srow1 = 64 + srow0;                                  \
    int slc = ((tid & 3) ^ ((tid >> 3) & 3)) * 8;   /* swizzled src chunk */   \
    const u16* gA0 = Aptr + (size_t)(m0 + srow0) * 1024 + slc;                 \
    const u16* gA1 = Aptr + (size_t)(m0 + srow1) * 1024 + slc;                 \
    const u16* gB0 = Bptr + (size_t)(n0 + srow0) * 1024 + slc;                 \
    const u16* gB1 = Bptr + (size_t)(n0 + srow1) * 1024 + slc;                 \
    int cq = (quad ^ ((l16 >> 1) & 3)) * 8;         /* frag phys chunk */      \
    GEMM_STAGE(gA0, gA1, gB0, gB1, 0, 0);                                      \
    for (int it = 0; it < 32; ++it) {                                          \
        int pb = it & 1;                                                       \
        __syncthreads();                  /* drains buf[pb] staging */         \
        bf8 af[4], bf[4];                                                      \
        _Pragma("unroll") for (int mi = 0; mi < 4; ++mi)                       \
            af[mi] = *(const bf8*)(As[pb] + (wr + mi * 16 + l16) * 32 + cq);   \
        _Pragma("unroll") for (int ni = 0; ni < 4; ++ni)                       \
            bf[ni] = *(const bf8*)(Bs[pb] + (wc + ni * 16 + l16) * 32 + cq);   \
        if (it < 31) GEMM_STAGE(gA0, gA1, gB0, gB1, (it + 1) * 32, pb ^ 1);    \
        _Pragma("unroll") for (int mi = 0; mi < 4; ++mi)                       \
            _Pragma("unroll") for (int ni = 0; ni < 4; ++ni)                   \
                acc[mi][ni] = mfma16(af[mi], bf[ni], acc[mi][ni]);             \
    }

// ---------------- QKV GEMM: [4096,1024] @ Wt[3072,1024] + bias ----------------
__global__ __launch_bounds__(256, 3) void k_qkv(const u16* __restrict__ Xb,
                                                const u16* __restrict__ WtA,
                                                const float* __restrict__ ba,
                                                u16* __restrict__ Qb,
                                                u16* __restrict__ Kb,
                                                u16* __restrict__ Vtb) {
    GEMM_CORE(Xb, WtA)
    int sel = n0 >> 10;                       // 0:Q 1:K 2:V (uniform per block)
    u16* dst = sel == 0 ? Qb : (sel == 1 ? Kb : Vtb);
    const float qs = 0.18033688011112042f;    // 0.125 * log2(e)
#pragma unroll
    for (int ni = 0; ni < 4; ++ni) {
        int n = n0 + wc + ni * 16 + l16;
        float bias = ba[n];
        int h = (n & 1023) >> 6;
        int d = n & 63;
#pragma unroll
        for (int mi = 0; mi < 4; ++mi)
#pragma unroll
            for (int r = 0; r < 4; ++r) {
                int m = m0 + wr + mi * 16 + quad * 4 + r;
                int bb = m >> 11, tt = m & 2047;
                float v = acc[mi][ni][r] + bias;
                size_t hb = (size_t)(bb * 16 + h);
                if (sel == 2)                             // V^T tiled
                    dst[hb * 131072 + (size_t)(tt >> 6) * 4096 + d * 64 + (tt & 63)] = f2b(v);
                else
                    dst[(hb * 2048 + tt) * 64 + d] =
                        f2b(sel == 0 ? v * qs : v);
            }
    }
}

// ---------------- proj GEMM: AO[4096,1024] @ WtP[1024,1024] + bias -> fp32 ----------------
__global__ __launch_bounds__(256, 3) void k_proj(const u16* __restrict__ AO,
                                                 const u16* __restrict__ WtP,
                                                 const float* __restrict__ bp,
                                                 float* __restrict__ out) {
    GEMM_CORE(AO, WtP)
#pragma unroll
    for (int ni = 0; ni < 4; ++ni) {
        int n = n0 + wc + ni * 16 + l16;
        float bias = bp[n];
#pragma unroll
        for (int mi = 0; mi < 4; ++mi)
#pragma unroll
            for (int r = 0; r < 4; ++r) {
                int m = m0 + wr + mi * 16 + quad * 4 + r;
                out[(size_t)m * 1024 + n] = acc[mi][ni][r] + bias;
            }
    }
}

// ---------------- flash attention (causal), 1-wave blocks, barrier-free ----------------
// Block = ONE wave handling FOUR 16-row q-tiles of one head:
//   qr_j = 16*t + 512*j (t = 0..31, j = 0..3), ktmax_j = (t>>2) + 8*j.
// K/V tiles staged to LDS via global_load_lds, double-buffered; staging is
// wave-private so there are NO barriers -- counted s_waitcnt vmcnt(16) leaves
// the next tile's 16 loads in flight across the whole compute phase (T4).
// K/V frag reads amortize over 4 q-tiles: per-cell LDS 148 -> 100 cycles.
// P buffer 4KB, pair-reused (cells 0,1 then 2,3); per-wave in-order DS +
// lgkm fence + sched_barrier(0) (rule #18) order the write->read->rewrite.

// stage swizzled K tile ([key][d], row swz (row>>2)&7) and V^T tile ([d][key],
// row swz row&7) into buf B. 16 gload_lds16 per wave = 16KB.
#define STAGE1(KT, B) do {                                                    \
    const u16* kt_ = Kh + (size_t)(KT) * 4096;                                \
    const u16* vt_ = Vh + (size_t)(KT) * 4096;                                \
    _Pragma("unroll") for (int i_ = 0; i_ < 8; ++i_) {                        \
        int ci_ = i_ * 64 + lane;                                             \
        gload_lds16(kt_ + (ci_ >> 3) * 64 +                                   \
                    (((ci_ & 7) ^ ((ci_ >> 5) & 7)) * 8), Ks[B] + ci_ * 8);   \
    }                                                                         \
    _Pragma("unroll") for (int i_ = 0; i_ < 8; ++i_) {                        \
        int ci_ = i_ * 64 + lane;                                             \
        gload_lds16(vt_ + (ci_ >> 3) * 64 +                                   \
                    (((ci_ & 7) ^ ((ci_ >> 3) & 7)) * 8), Vs[B] + ci_ * 8);   \
    }                                                                         \
} while (0)

// QK + softmax for one q-tile into P buffer (XOR-chunk swizzled, R12-verified).
#define QK_SOFT(KT, KF, QF0, QF1, LI, QROW, KTM, PBUF) do {                   \
    int kb_ = (KT) * 64;                                                      \
    bool diag_ = ((KT) == (KTM));                                             \
    f32x4 s_acc[4];                                                           \
    _Pragma("unroll") for (int s = 0; s < 4; ++s)                             \
        _Pragma("unroll") for (int r = 0; r < 4; ++r) s_acc[s][r] = 0.f;      \
    _Pragma("unroll") for (int sub = 0; sub < 4; ++sub) {                     \
        s_acc[sub] = mfma16(QF0, KF[sub][0], s_acc[sub]);                     \
        s_acc[sub] = mfma16(QF1, KF[sub][1], s_acc[sub]);                     \
    }                                                                         \
    _Pragma("unroll") for (int r = 0; r < 4; ++r) {                           \
        float p[4];                                                           \
        if (diag_) {                                                          \
            int qg_ = (QROW) + quad * 4 + r;                                  \
            _Pragma("unroll") for (int sub = 0; sub < 4; ++sub) {             \
                int key_ = kb_ + 4 * l16 + sub;                               \
                p[sub] = fexp2(key_ <= qg_ ? s_acc[sub][r] : -1e30f);         \
            }                                                                 \
        } else {                                                              \
            _Pragma("unroll") for (int sub = 0; sub < 4; ++sub)               \
                p[sub] = fexp2(s_acc[sub][r]);                                \
        }                                                                     \
        LI[r] += (p[0] + p[1]) + (p[2] + p[3]);                               \
        u16x4s pk_;                                                           \
        _Pragma("unroll") for (int sub = 0; sub < 4; ++sub)                   \
            pk_.v[sub] = f2b(p[sub]);                                         \
        int prow_ = quad * 4 + r;                                             \
        *(u16x4s*)&PBUF[prow_][(((l16 >> 1) ^ (prow_ & 7)) << 3) +            \
                               ((l16 & 1) << 2)] = pk_;   /* ds_write_b64 */  \
    }                                                                         \
} while (0)

#define PV_ACC(VF, PBUF, OACC) do {                                           \
    int xp_ = l16 & 7;                                                        \
    bf8 pf0 = *(const bf8*)&PBUF[l16][(quad ^ xp_) << 3];                     \
    bf8 pf1 = *(const bf8*)&PBUF[l16][((4 + quad) ^ xp_) << 3];               \
    _Pragma("unroll") for (int dt = 0; dt < 4; ++dt) {                        \
        OACC[dt] = mfma16(pf0, VF[dt][0], OACC[dt]);                          \
        OACC[dt] = mfma16(pf1, VF[dt][1], OACC[dt]);                          \
    }                                                                         \
} while (0)

#define LREDUCE(LI, LINV) do {                                                \
    _Pragma("unroll") for (int r = 0; r < 4; ++r) {                           \
        float s_ = LI[r];                                                     \
        s_ += __shfl_xor(s_, 1, 64); s_ += __shfl_xor(s_, 2, 64);             \
        s_ += __shfl_xor(s_, 4, 64); s_ += __shfl_xor(s_, 8, 64);             \
        LINV[r] = __builtin_amdgcn_rcpf(s_);                                  \
    }                                                                         \
} while (0)

#define STORE_O(OA, LINV, QR) do {                                            \
    _Pragma("unroll") for (int dt = 0; dt < 4; ++dt)                          \
        _Pragma("unroll") for (int r = 0; r < 4; ++r) {                       \
            int off_ = quad * 4 + r;                                          \
            size_t row_ = (size_t)b * 2048 + (QR) + off_;                     \
            AO[row_ * 1024 + h * 64 + dt * 16 + l16] =                        \
                f2b(OA[dt][r] * LINV[r]);                                     \
        }                                                                     \
} while (0)

__global__ __launch_bounds__(64, 1) void k_attn(const u16* __restrict__ Qb,
                                                const u16* __restrict__ Kb,
                                                const u16* __restrict__ Vtb,
                                                u16* __restrict__ AO) {
    // 1024 blocks; same-head blocks share id%8 (XCD L2 affinity).
    int id = blockIdx.x;                     // 0..1023
    int bh = (id & 7) * 4 + ((id >> 3) & 3); // head-batch 0..31
    int t  = id >> 5;                        // 0..31
    int lane = threadIdx.x & 63, l16 = lane & 15, quad = lane >> 4;

    const u16* Qh = Qb  + (size_t)bh * 131072;
    const u16* Kh = Kb  + (size_t)bh * 131072;
    const u16* Vh = Vtb + (size_t)bh * 131072;      // V^T tiled: [kt][d][t64]

    __shared__ u16 Ks[2][4096];              // swizzled [key][d] image, 8KB each
    __shared__ u16 Vs[2][4096];              // swizzled [d][key] image
    __shared__ u16 P[2][16][64];             // pair-reused, XOR-swizzled

    int qr0 = t * 16, qr1 = qr0 + 512, qr2 = qr0 + 1024, qr3 = qr0 + 1536;
    int ktm0 = t >> 2, ktm1 = ktm0 + 8, ktm2 = ktm0 + 16, ktm3 = ktm0 + 24;

    bf8 qf0[4], qf1[4];
#pragma unroll
    for (int j = 0; j < 4; ++j) {
        int qr = t * 16 + j * 512;
        qf0[j] = *(const bf8*)(Qh + (size_t)(qr + l16) * 64 + quad * 8);
        qf1[j] = *(const bf8*)(Qh + (size_t)(qr + l16) * 64 + 32 + quad * 8);
    }

    float li0[4], li1[4], li2[4], li3[4];
    f32x4 oa0[4], oa1[4], oa2[4], oa3[4];
#pragma unroll
    for (int r = 0; r < 4; ++r) { li0[r] = li1[r] = li2[r] = li3[r] = 0.f; }
#pragma unroll
    for (int dt = 0; dt < 4; ++dt)
#pragma unroll
        for (int r = 0; r < 4; ++r) {
            oa0[dt][r] = 0.f; oa1[dt][r] = 0.f;
            oa2[dt][r] = 0.f; oa3[dt][r] = 0.f;
        }

    int xsw = (l16 & 7) * 8;                 // read-side XOR term, u16 units

    STAGE1(0, 0);
    int nkt = ktm3 + 1;                      // 25..32, uniform per block
    for (int kt = 0; kt < nkt; ++kt) {
        int pb = kt & 1;
        if (kt + 1 < nkt) {
            STAGE1(kt + 1, pb ^ 1);          // issue next tile first
            asm volatile("s_waitcnt vmcnt(16)" ::: "memory");  // cur tile done
        } else {
            asm volatile("s_waitcnt vmcnt(0)" ::: "memory");
        }
        __builtin_amdgcn_sched_barrier(0);   // keep ds_reads after the wait

        // K/V fragments from swizzled LDS (physical chunk = logical ^ swz(row))
        bf8 kf[4][2], vf[4][2];
        const u16* kb_ = Ks[pb];
        const u16* vb_ = Vs[pb];
#pragma unroll
        for (int sub = 0; sub < 4; ++sub)
#pragma unroll
            for (int ks = 0; ks < 2; ++ks)
                kf[sub][ks] = *(const bf8*)(kb_ + (4 * l16 + sub) * 64 +
                                            (((ks * 32 + quad * 8)) ^ xsw));
#pragma unroll
        for (int dt = 0; dt < 4; ++dt)
#pragma unroll
            for (int ks = 0; ks < 2; ++ks)
                vf[dt][ks] = *(const bf8*)(vb_ + (dt * 16 + l16) * 64 +
                                           (((ks * 32 + quad * 8)) ^ xsw));

        bool a0 = (kt <= ktm0), a1 = (kt <= ktm1), a2 = (kt <= ktm2);

        // pair 1: cells 0,1
        if (a0) QK_SOFT(kt, kf, qf0[0], qf1[0], li0, qr0, ktm0, P[0]);
        if (a1) QK_SOFT(kt, kf, qf0[1], qf1[1], li1, qr1, ktm1, P[1]);
        asm volatile("s_waitcnt lgkmcnt(0)" ::: "memory");  // P write->read
        __builtin_amdgcn_sched_barrier(0);
        if (a0) PV_ACC(vf, P[0], oa0);
        if (a1) PV_ACC(vf, P[1], oa1);

        // pair 2: cells 2,3 (reuse P; per-wave in-order DS keeps RAW/WAR safe)
        if (a2) QK_SOFT(kt, kf, qf0[2], qf1[2], li2, qr2, ktm2, P[0]);
        QK_SOFT(kt, kf, qf0[3], qf1[3], li3, qr3, ktm3, P[1]);
        asm volatile("s_waitcnt lgkmcnt(0)" ::: "memory");
        __builtin_amdgcn_sched_barrier(0);
        if (a2) PV_ACC(vf, P[0], oa2);
        PV_ACC(vf, P[1], oa3);
    }

    float lv0[4], lv1[4], lv2[4], lv3[4];
    LREDUCE(li0, lv0); LREDUCE(li1, lv1); LREDUCE(li2, lv2); LREDUCE(li3, lv3);

    int b = bh >> 4, h = bh & 15;
    STORE_O(oa0, lv0, qr0);
    STORE_O(oa1, lv1, qr1);
    STORE_O(oa2, lv2, qr2);
    STORE_O(oa3, lv3, qr3);
}

extern "C" void kernel_launch(void* const* d_in, const int* in_sizes, int n_in,
                              void* d_out, int out_size, void* d_ws, size_t ws_size,
                              hipStream_t stream) {
    const float* x  = (const float*)d_in[0];
    const float* Wa = (const float*)d_in[1];
    const float* ba = (const float*)d_in[2];
    const float* Wp = (const float*)d_in[3];
    const float* bp = (const float*)d_in[4];
    float* out = (float*)d_out;

    char* ws = (char*)d_ws;
    const size_t MB = 1024 * 1024;
    u16* Xb  = (u16*)(ws);             // 8 MB  x as bf16   (reused as AO later)
    u16* WtA = (u16*)(ws + 8  * MB);   // 6 MB  W_attn^T bf16
    u16* WtP = (u16*)(ws + 14 * MB);   // 2 MB  W_proj^T bf16
    u16* Qb  = (u16*)(ws + 16 * MB);   // 8 MB  [B*H][T][D], pre-scaled
    u16* Kb  = (u16*)(ws + 24 * MB);   // 8 MB  [B*H][T][D]
    u16* Vtb = (u16*)(ws + 32 * MB);   // 8 MB  [B*H][32][64][64] tiled V^T
    u16* AO  = Xb;                     // alias: Xb dead after k_qkv (stream-ordered)

    k_prep<<<dim3(5120),    dim3(256), 0, stream>>>(x, Wa, Wp, Xb, WtA, WtP);
    k_qkv <<<dim3(32, 24),  dim3(256), 0, stream>>>(Xb, WtA, ba, Qb, Kb, Vtb);
    k_attn<<<dim3(1024),    dim3(64),  0, stream>>>(Qb, Kb, Vtb, AO);
    k_proj<<<dim3(32, 8),   dim3(256), 0, stream>>>(AO, WtP, bp, out);
}

// Round 6
// 182.109 us; speedup vs baseline: 1.0802x; 1.0802x over previous
//
#include <hip/hip_runtime.h>

// Fused causal self-attention block, MI355X gfx950.
// B=2, T=2048, E=1024, H=16, D=64.
// Verified 16x16x32 layouts (m89/m91): A[m=lane&15][k=(lane>>4)*8+j],
//   B[k=(lane>>4)*8+j][n=lane&15], C/D[row=(lane>>4)*4+r][col=lane&15].
// 32x32x16 layouts (m74/m101): A[m=lane&31][k=(lane>>5)*8+j],
//   B[k=(lane>>5)*8+j][n=lane&31], C/D[col=lane&31, row=(reg&3)+8*(reg>>2)+4*(lane>>5)].
// R12 FAILED: per-lane global K/V frag loads = L1 transaction-bound; keep
//   global_load_lds staging. Verified: XOR-swizzled LDS images.
// R13/14 (landed, attn ~41us, total 173.4): swizzled P + native-cast f2b.
// R15 FAILED (65us): 1-wave blocks -> 1 wave/SIMD -> latency-bound (occ 8.9%,
//   MfmaUtil 10). LESSON: need >=2 waves/SIMD; cells/wave trades against that.
// R16 (this round): 32x32 MFMA + swapped QK^T (S^T = mfma(K,Q), guide T12):
//   2x FLOP per LDS byte (same 16B/lane frags), lane owns one q-column ->
//   l_i lane-local, P repack fully in-register (cvt_pk + shfl_xor(32) +
//   cndmask) -- NO P LDS, NO per-iter lgkm fences. 2048 waves (1 cell=32 rows
//   per wave), 4-wave blocks share K/V staging (R13 structure), 2 blocks/CU
//   = 2 waves/SIMD. Epilogue O^T->O transpose via freed KV LDS.

typedef unsigned short u16;
typedef unsigned int u32;
typedef __bf16 bf8 __attribute__((ext_vector_type(8)));
typedef float f32x4 __attribute__((ext_vector_type(4)));
typedef float f32x16 __attribute__((ext_vector_type(16)));
typedef u32 u32x4v __attribute__((ext_vector_type(4)));

__device__ __forceinline__ u16 f2b(float f) {
    return __builtin_bit_cast(u16, (__bf16)f);         // RNE
}

__device__ __forceinline__ u32 pk2(float lo, float hi) {
    return (u32)f2b(lo) | ((u32)f2b(hi) << 16);        // v_cvt_pk_bf16_f32
}

__device__ __forceinline__ f32x4 mfma16(bf8 a, bf8 b, f32x4 c) {
    return __builtin_amdgcn_mfma_f32_16x16x32_bf16(a, b, c, 0, 0, 0);
}

__device__ __forceinline__ f32x16 mfma32(bf8 a, bf8 b, f32x16 c) {
    return __builtin_amdgcn_mfma_f32_32x32x16_bf16(a, b, c, 0, 0, 0);
}

__device__ __forceinline__ float fexp2(float x) {
    return __builtin_amdgcn_exp2f(x);                  // v_exp_f32
}

// async global->LDS, 16B per lane. LDS dest must be wave-uniform base + lane*16.
__device__ __forceinline__ void gload_lds16(const u16* g, u16* l) {
    __builtin_amdgcn_global_load_lds(
        (__attribute__((address_space(1))) void*)(g),
        (__attribute__((address_space(3))) void*)(l), 16, 0, 0);
}

// ---------------- prep: x->bf16 convert + both weight transposes ----------------
__global__ __launch_bounds__(256) void k_prep(const float* __restrict__ x,
                                              const float* __restrict__ Wa,
                                              const float* __restrict__ Wp,
                                              u16* __restrict__ Xb,
                                              u16* __restrict__ WtA,
                                              u16* __restrict__ WtP) {
    __shared__ float tile[64][65];
    int id = blockIdx.x, t = threadIdx.x;
    if (id < 4096) {                         // convert 4 floats/thread
        int i = id * 256 + t;
        float4 v = ((const float4*)x)[i];
        ushort4 o;
        o.x = f2b(v.x); o.y = f2b(v.y); o.z = f2b(v.z); o.w = f2b(v.w);
        ((ushort4*)Xb)[i] = o;
        return;
    }
    const float* in; u16* out; int N, j;
    if (id < 4864) { j = id - 4096; in = Wa; out = WtA; N = 3072; }
    else           { j = id - 4864; in = Wp; out = WtP; N = 1024; }
    int k0 = (j & 15) * 64, n0 = (j >> 4) * 64;
    int c = t & 63, r0 = t >> 6;
#pragma unroll
    for (int i = 0; i < 16; ++i) {
        int r = r0 + i * 4;
        tile[r][c] = in[(size_t)(k0 + r) * N + n0 + c];
    }
    __syncthreads();
#pragma unroll
    for (int i = 0; i < 16; ++i) {
        int r = r0 + i * 4;
        out[(size_t)(n0 + r) * 1024 + k0 + c] = f2b(tile[c][r]);
    }
}

// =====================================================================
// GEMM core v2 (unchanged from R13/14): C[128x128]/block, dbuf LDS,
// 1 barrier/K-step, XOR-swizzled images.
// =====================================================================
#define GEMM_STAGE(GA0, GA1, GB0, GB1, K, B)                                   \
    do {                                                                       \
        gload_lds16(GA0 + (K), As[B] + tid * 8);                               \
        gload_lds16(GA1 + (K), As[B] + (256 + tid) * 8);                       \
        gload_lds16(GB0 + (K), Bs[B] + tid * 8);                               \
        gload_lds16(GB1 + (K), Bs[B] + (256 + tid) * 8);                       \
    } while (0)

#define GEMM_CORE(Aptr, Bptr)                                                  \
    int tid = threadIdx.x;                                                     \
    int w = tid >> 6, lane = tid & 63, l16 = lane & 15, quad = lane >> 4;      \
    int m0 = blockIdx.x * 128, n0 = blockIdx.y * 128;                          \
    int wr = (w >> 1) * 64, wc = (w & 1) * 64;                                 \
    __shared__ u16 As[2][128 * 32];                                            \
    __shared__ u16 Bs[2][128 * 32];                                            \
    f32x4 acc[4][4];                                                           \
    _Pragma("unroll") for (int mi = 0; mi < 4; ++mi)                           \
        _Pragma("unroll") for (int ni = 0; ni < 4; ++ni)                       \
            _Pragma("unroll") for (int r = 0; r < 4; ++r) acc[mi][ni][r] = 0.f;\
    int srow0 = tid >> 2, srow1 = 64 + srow0;                                  \
    int slc = ((tid & 3) ^ ((tid >> 3) & 3)) * 8;   /* swizzled src chunk */   \
    const u16* gA0 = Aptr + (size_t)(m0 + srow0) * 1024 + slc;                 \
    const u16* gA1 = Aptr + (size_t)(m0 + srow1) * 1024 + slc;                 \
    const u16* gB0 = Bptr + (size_t)(n0 + srow0) * 1024 + slc;                 \
    const u16* gB1 = Bptr + (size_t)(n0 + srow1) * 1024 + slc;                 \
    int cq = (quad ^ ((l16 >> 1) & 3)) * 8;         /* frag phys chunk */      \
    GEMM_STAGE(gA0, gA1, gB0, gB1, 0, 0);                                      \
    for (int it = 0; it < 32; ++it) {                                          \
        int pb = it & 1;                                                       \
        __syncthreads();                  /* drains buf[pb] staging */         \
        bf8 af[4], bf[4];                                                      \
        _Pragma("unroll") for (int mi = 0; mi < 4; ++mi)                       \
            af[mi] = *(const bf8*)(As[pb] + (wr + mi * 16 + l16) * 32 + cq);   \
        _Pragma("unroll") for (int ni = 0; ni < 4; ++ni)                       \
            bf[ni] = *(const bf8*)(Bs[pb] + (wc + ni * 16 + l16) * 32 + cq);   \
        if (it < 31) GEMM_STAGE(gA0, gA1, gB0, gB1, (it + 1) * 32, pb ^ 1);    \
        _Pragma("unroll") for (int mi = 0; mi < 4; ++mi)                       \
            _Pragma("unroll") for (int ni = 0; ni < 4; ++ni)                   \
                acc[mi][ni] = mfma16(af[mi], bf[ni], acc[mi][ni]);             \
    }

// ---------------- QKV GEMM: [4096,1024] @ Wt[3072,1024] + bias ----------------
__global__ __launch_bounds__(256, 3) void k_qkv(const u16* __restrict__ Xb,
                                                const u16* __restrict__ WtA,
                                                const float* __restrict__ ba,
                                                u16* __restrict__ Qb,
                                                u16* __restrict__ Kb,
                                                u16* __restrict__ Vtb) {
    GEMM_CORE(Xb, WtA)
    int sel = n0 >> 10;                       // 0:Q 1:K 2:V (uniform per block)
    u16* dst = sel == 0 ? Qb : (sel == 1 ? Kb : Vtb);
    const float qs = 0.18033688011112042f;    // 0.125 * log2(e)
#pragma unroll
    for (int ni = 0; ni < 4; ++ni) {
        int n = n0 + wc + ni * 16 + l16;
        float bias = ba[n];
        int h = (n & 1023) >> 6;
        int d = n & 63;
#pragma unroll
        for (int mi = 0; mi < 4; ++mi)
#pragma unroll
            for (int r = 0; r < 4; ++r) {
                int m = m0 + wr + mi * 16 + quad * 4 + r;
                int bb = m >> 11, tt = m & 2047;
                float v = acc[mi][ni][r] + bias;
                size_t hb = (size_t)(bb * 16 + h);
                if (sel == 2)                             // V^T tiled
                    dst[hb * 131072 + (size_t)(tt >> 6) * 4096 + d * 64 + (tt & 63)] = f2b(v);
                else
                    dst[(hb * 2048 + tt) * 64 + d] =
                        f2b(sel == 0 ? v * qs : v);
            }
    }
}

// ---------------- proj GEMM: AO[4096,1024] @ WtP[1024,1024] + bias -> fp32 ----------------
__global__ __launch_bounds__(256, 3) void k_proj(const u16* __restrict__ AO,
                                                 const u16* __restrict__ WtP,
                                                 const float* __restrict__ bp,
                                                 float* __restrict__ out) {
    GEMM_CORE(AO, WtP)
#pragma unroll
    for (int ni = 0; ni < 4; ++ni) {
        int n = n0 + wc + ni * 16 + l16;
        float bias = bp[n];
#pragma unroll
        for (int mi = 0; mi < 4; ++mi)
#pragma unroll
            for (int r = 0; r < 4; ++r) {
                int m = m0 + wr + mi * 16 + quad * 4 + r;
                out[(size_t)m * 1024 + n] = acc[mi][ni][r] + bias;
            }
    }
}

// ---------------- flash attention (causal), 32x32 swapped-QK^T ----------------
// Block = 4 waves, one head; wave w owns ONE 32-row q-tile tq = t + 16w
// (qr = 32*tq), so K/V tiles are shared via LDS staging exactly as R13.
// Per 64-key tile: S^T[key][q] = mfma32(K-frag, Q^T-frag) -> lane holds
// col q=lane&31, rows key=(reg&3)+8*(reg>>2)+4h. exp2 in place; l_i is
// LANE-LOCAL. P^T->B-frag repack in registers: pk2 pairs + shfl_xor(32)
// + half-uniform cndmask (T12 pattern). PV: O^T = mfma32(V^T-frag, P^T-frag).
// Epilogue: O^T -> O transpose through freed KV LDS, coalesced b128 stores.

#define STAGE(KT, B) do {                                                     \
    int ci0_ = tid, ci1_ = 256 + tid;                                         \
    const u16* kt_ = Kh + (size_t)(KT) * 4096;                                \
    gload_lds16(kt_ + (ci0_ >> 3) * 64 +                                      \
                (((ci0_ & 7) ^ ((ci0_ >> 5) & 7)) * 8), KV[B][0] + ci0_ * 8); \
    gload_lds16(kt_ + (ci1_ >> 3) * 64 +                                      \
                (((ci1_ & 7) ^ ((ci1_ >> 5) & 7)) * 8), KV[B][0] + ci1_ * 8); \
    const u16* vt_ = Vh + (size_t)(KT) * 4096;                                \
    gload_lds16(vt_ + (ci0_ >> 3) * 64 +                                      \
                (((ci0_ & 7) ^ ((ci0_ >> 3) & 7)) * 8), KV[B][1] + ci0_ * 8); \
    gload_lds16(vt_ + (ci1_ >> 3) * 64 +                                      \
                (((ci1_ & 7) ^ ((ci1_ >> 3) & 7)) * 8), KV[B][1] + ci1_ * 8); \
} while (0)

// one PV k-slice SG (global keys 16*SG..+15): V^T frags for both d-blocks,
// P^T frag BFR (4 u32 = bf16x8).
#define PVSTEP(SG, BFR) do {                                                  \
    bf8 va_ = *(const bf8*)(vb_ + l31 * 64 +                                  \
                            (((2 * (SG) + h) ^ vswz) * 8));                   \
    bf8 vc_ = *(const bf8*)(vb_ + (32 + l31) * 64 +                           \
                            (((2 * (SG) + h) ^ vswz) * 8));                   \
    bf8 pf_ = __builtin_bit_cast(bf8, BFR);                                   \
    oT0 = mfma32(va_, pf_, oT0);                                              \
    oT1 = mfma32(vc_, pf_, oT1);                                              \
} while (0)

// build the two B-frags (sub-slices sigma=0,1) of one key-block from packed
// own (PK) / partner (PP) u32s. Half-uniform h selects the exchange pattern.
#define BFRAGS(PK, PP, B0, B1) do {                                           \
    B0[0] = h ? PP[2] : PK[0]; B0[1] = h ? PP[3] : PK[1];                     \
    B0[2] = h ? PK[2] : PP[0]; B0[3] = h ? PK[3] : PP[1];                     \
    B1[0] = h ? PP[6] : PK[4]; B1[1] = h ? PP[7] : PK[5];                     \
    B1[2] = h ? PK[6] : PP[4]; B1[3] = h ? PK[7] : PP[5];                     \
} while (0)

__global__ __launch_bounds__(256, 2) void k_attn(const u16* __restrict__ Qb,
                                                 const u16* __restrict__ Kb,
                                                 const u16* __restrict__ Vtb,
                                                 u16* __restrict__ AO) {
    // 512 blocks; same-head blocks share id%8 (XCD L2 affinity). Longest first.
    int id = blockIdx.x;                     // 0..511
    int bh = (id & 7) * 4 + ((id >> 3) & 3); // head-batch 0..31
    int t  = 15 - (id >> 5);                 // 0..15
    int tid = threadIdx.x;
    int w = tid >> 6, lane = tid & 63, l31 = lane & 31, h = lane >> 5;

    const u16* Qh = Qb  + (size_t)bh * 131072;
    const u16* Kh = Kb  + (size_t)bh * 131072;
    const u16* Vh = Vtb + (size_t)bh * 131072;      // V^T tiled: [kt][d][t64]

    __shared__ u16 KV[2][2][4096];           // [buf][K|V][swizzled image] 32KB

    int tq = t + 16 * w;                     // q-tile 0..63
    int qr = tq * 32;
    int ktmax = tq >> 1;                     // this wave's last key-tile
    int nkt = ((t + 48) >> 1) + 1;           // block-uniform loop bound

    // Q^T fragments (B-operand): lane reads its own q-row, 4 d-slices.
    bf8 qf[4];
#pragma unroll
    for (int s = 0; s < 4; ++s)
        qf[s] = *(const bf8*)(Qh + (size_t)(qr + l31) * 64 + s * 16 + h * 8);

    float l_acc = 0.f;
    f32x16 oT0, oT1;
#pragma unroll
    for (int r = 0; r < 16; ++r) { oT0[r] = 0.f; oT1[r] = 0.f; }

    int kswz = (l31 >> 2) & 7;               // Ks image row-swizzle selector
    int vswz = l31 & 7;                      // Vs image row-swizzle selector

    STAGE(0, 0);
    for (int kt = 0; kt < nkt; ++kt) {
        int pb = kt & 1;
        __syncthreads();                     // drains buf[pb] staging
        if (kt + 1 < nkt) STAGE(kt + 1, pb ^ 1);

        if (kt <= ktmax) {
            const u16* kb_ = KV[pb][0];
            const u16* vb_ = KV[pb][1];
            bool diag = (kt == ktmax);
            bool doK1 = !(diag && ((tq & 1) == 0));  // upper kblk fully masked?

            // ---- QK^T: S^T = K · Q^T ----
            f32x16 sT0, sT1;
#pragma unroll
            for (int r = 0; r < 16; ++r) { sT0[r] = 0.f; sT1[r] = 0.f; }
#pragma unroll
            for (int s = 0; s < 4; ++s) {
                bf8 kf = *(const bf8*)(kb_ + l31 * 64 +
                                       (((2 * s + h) ^ kswz) * 8));
                sT0 = mfma32(kf, qf[s], sT0);
            }
            if (doK1) {
#pragma unroll
                for (int s = 0; s < 4; ++s) {
                    bf8 kf = *(const bf8*)(kb_ + (32 + l31) * 64 +
                                           (((2 * s + h) ^ kswz) * 8));
                    sT1 = mfma32(kf, qf[s], sT1);
                }
            }

            // ---- softmax (exp2, Q pre-scaled; mask only on diag tile) ----
            int kb0 = kt * 64, qg = qr + l31;
            if (diag) {
#pragma unroll
                for (int r = 0; r < 16; ++r) {
                    int krow = kb0 + (r & 3) + 8 * (r >> 2) + 4 * h;
                    sT0[r] = fexp2(krow <= qg ? sT0[r] : -1e30f);
                    l_acc += sT0[r];
                }
                if (doK1) {
#pragma unroll
                    for (int r = 0; r < 16; ++r) {
                        int krow = kb0 + 32 + (r & 3) + 8 * (r >> 2) + 4 * h;
                        sT1[r] = fexp2(krow <= qg ? sT1[r] : -1e30f);
                        l_acc += sT1[r];
                    }
                }
            } else {
#pragma unroll
                for (int r = 0; r < 16; ++r) {
                    sT0[r] = fexp2(sT0[r]); l_acc += sT0[r];
                }
#pragma unroll
                for (int r = 0; r < 16; ++r) {
                    sT1[r] = fexp2(sT1[r]); l_acc += sT1[r];
                }
            }

            // ---- P^T repack (in-register, T12 pattern) + PV ----
            u32 pka[8], ppa[8];
#pragma unroll
            for (int j = 0; j < 8; ++j)
                pka[j] = pk2(sT0[2 * j], sT0[2 * j + 1]);
#pragma unroll
            for (int j = 0; j < 8; ++j)
                ppa[j] = __shfl_xor(pka[j], 32, 64);
            u32x4v bf0, bf1;
            BFRAGS(pka, ppa, bf0, bf1);
            PVSTEP(0, bf0);
            PVSTEP(1, bf1);
            if (doK1) {
                u32 pkb[8], ppb[8];
#pragma unroll
                for (int j = 0; j < 8; ++j)
                    pkb[j] = pk2(sT1[2 * j], sT1[2 * j + 1]);
#pragma unroll
                for (int j = 0; j < 8; ++j)
                    ppb[j] = __shfl_xor(pkb[j], 32, 64);
                u32x4v bg0, bg1;
                BFRAGS(pkb, ppb, bg0, bg1);
                PVSTEP(2, bg0);
                PVSTEP(3, bg1);
            }
        }
    }

    // ---- epilogue: normalize, transpose O^T -> O via freed KV LDS ----
    __syncthreads();                         // all waves done reading KV
    float lsum = l_acc + __shfl_xor(l_acc, 32, 64);
    float linv = __builtin_amdgcn_rcpf(lsum);

    u32* Ot = (u32*)(&KV[0][0][0]) + w * 1152;   // [32 q][36-pad u32 cols]
#pragma unroll
    for (int j = 0; j < 8; ++j) {
        int col = 4 * (j >> 1) + 2 * h + (j & 1);   // d/2 within 32-block
        Ot[l31 * 36 + col]      = pk2(oT0[2 * j] * linv, oT0[2 * j + 1] * linv);
        Ot[l31 * 36 + 16 + col] = pk2(oT1[2 * j] * linv, oT1[2 * j + 1] * linv);
    }
    asm volatile("s_waitcnt lgkmcnt(0)" ::: "memory");
    __builtin_amdgcn_sched_barrier(0);       // rule #18: pin reads after fence

    int q2 = lane >> 1, half = lane & 1;
    int eb = bh >> 4, eh = bh & 15;
    size_t row = (size_t)eb * 2048 + qr + q2;
    const u32* src = Ot + q2 * 36 + half * 16;
    u32* dstg = (u32*)(AO + row * 1024 + eh * 64) + half * 16;
#pragma unroll
    for (int c = 0; c < 4; ++c)
        *(u32x4v*)(dstg + 4 * c) = *(const u32x4v*)(src + 4 * c);
}

extern "C" void kernel_launch(void* const* d_in, const int* in_sizes, int n_in,
                              void* d_out, int out_size, void* d_ws, size_t ws_size,
                              hipStream_t stream) {
    const float* x  = (const float*)d_in[0];
    const float* Wa = (const float*)d_in[1];
    const float* ba = (const float*)d_in[2];
    const float* Wp = (const float*)d_in[3];
    const float* bp = (const float*)d_in[4];
    float* out = (float*)d_out;

    char* ws = (char*)d_ws;
    const size_t MB = 1024 * 1024;
    u16* Xb  = (u16*)(ws);             // 8 MB  x as bf16   (reused as AO later)
    u16* WtA = (u16*)(ws + 8  * MB);   // 6 MB  W_attn^T bf16
    u16* WtP = (u16*)(ws + 14 * MB);   // 2 MB  W_proj^T bf16
    u16* Qb  = (u16*)(ws + 16 * MB);   // 8 MB  [B*H][T][D], pre-scaled
    u16* Kb  = (u16*)(ws + 24 * MB);   // 8 MB  [B*H][T][D]
    u16* Vtb = (u16*)(ws + 32 * MB);   // 8 MB  [B*H][32][64][64] tiled V^T
    u16* AO  = Xb;                     // alias: Xb dead after k_qkv (stream-ordered)

    k_prep<<<dim3(5120),    dim3(256), 0, stream>>>(x, Wa, Wp, Xb, WtA, WtP);
    k_qkv <<<dim3(32, 24),  dim3(256), 0, stream>>>(Xb, WtA, ba, Qb, Kb, Vtb);
    k_attn<<<dim3(512),     dim3(256), 0, stream>>>(Qb, Kb, Vtb, AO);
    k_proj<<<dim3(32, 8),   dim3(256), 0, stream>>>(AO, WtP, bp, out);
}

// Round 7
// 177.400 us; speedup vs baseline: 1.1089x; 1.0265x over previous
//
#include <hip/hip_runtime.h>

// Fused causal self-attention block, MI355X gfx950.
// B=2, T=2048, E=1024, H=16, D=64.
// Verified 16x16x32 layouts (m89/m91): A[m=lane&15][k=(lane>>4)*8+j],
//   B[k=(lane>>4)*8+j][n=lane&15], C/D[row=(lane>>4)*4+r][col=lane&15].
// 32x32x16 layouts (m74/m101): A[m=lane&31][k=(lane>>5)*8+j],
//   B[k=(lane>>5)*8+j][n=lane&31], C/D[col=lane&31, row=(reg&3)+8*(reg>>2)+4*(lane>>5)].
// R12 FAILED: per-lane global K/V frag loads = L1 transaction-bound; keep
//   global_load_lds staging.
// R13/14 (landed, attn ~41us): 16x16 + swizzled P LDS + native-cast f2b.
// R15 FAILED (65us): 1 wave/SIMD latency-bound. Need >=2 waves/SIMD.
// R16 (50.5us, correct): 32x32 swapped-QK^T, in-register P repack. Post-mortem:
//   (a) K image staged with (row>>2)&7 swizzle but read rows = l31 -> lanes
//       0-3 share bank group = 4-way conflict (2.23M). V ((row&7)) was clean.
//   (b) shfl_xor repack = DS-pipe op, ~480 extra LDS cyc/CU-iter.
//   (c) wall 4000 cyc/iter vs 1900 modeled busy -> per-barrier serialization.
// R17 (this round): (a) K swizzle -> row&7 (match V); (b) repack via
//   v_permlane32_swap_b32 (VALU; 4 swaps replace 8 shfl + 8 cndmask --
//   mapping verified against R16-passed BFRAGS); (c) KVBLK=128: stage two
//   64-key tiles per barrier (LDS 64KB, 2 blocks/CU), inner 2-step unroll
//   of the verified 64-key body -> half the serialization rounds.

typedef unsigned short u16;
typedef unsigned int u32;
typedef __bf16 bf8 __attribute__((ext_vector_type(8)));
typedef float f32x4 __attribute__((ext_vector_type(4)));
typedef float f32x16 __attribute__((ext_vector_type(16)));
typedef u32 u32x4v __attribute__((ext_vector_type(4)));

__device__ __forceinline__ u16 f2b(float f) {
    return __builtin_bit_cast(u16, (__bf16)f);         // RNE
}

__device__ __forceinline__ u32 pk2(float lo, float hi) {
    return (u32)f2b(lo) | ((u32)f2b(hi) << 16);
}

__device__ __forceinline__ f32x4 mfma16(bf8 a, bf8 b, f32x4 c) {
    return __builtin_amdgcn_mfma_f32_16x16x32_bf16(a, b, c, 0, 0, 0);
}

__device__ __forceinline__ f32x16 mfma32(bf8 a, bf8 b, f32x16 c) {
    return __builtin_amdgcn_mfma_f32_32x32x16_bf16(a, b, c, 0, 0, 0);
}

__device__ __forceinline__ float fexp2(float x) {
    return __builtin_amdgcn_exp2f(x);                  // v_exp_f32
}

// a' = [a.lo31, b.lo31]; b' = [a.hi31, b.hi31]  (VALU cross-half exchange)
__device__ __forceinline__ void pl32swap(u32& a, u32& b) {
    asm("v_permlane32_swap_b32 %0, %1" : "+v"(a), "+v"(b));
}

// async global->LDS, 16B per lane. LDS dest must be wave-uniform base + lane*16.
__device__ __forceinline__ void gload_lds16(const u16* g, u16* l) {
    __builtin_amdgcn_global_load_lds(
        (__attribute__((address_space(1))) void*)(g),
        (__attribute__((address_space(3))) void*)(l), 16, 0, 0);
}

// ---------------- prep: x->bf16 convert + both weight transposes ----------------
__global__ __launch_bounds__(256) void k_prep(const float* __restrict__ x,
                                              const float* __restrict__ Wa,
                                              const float* __restrict__ Wp,
                                              u16* __restrict__ Xb,
                                              u16* __restrict__ WtA,
                                              u16* __restrict__ WtP) {
    __shared__ float tile[64][65];
    int id = blockIdx.x, t = threadIdx.x;
    if (id < 4096) {                         // convert 4 floats/thread
        int i = id * 256 + t;
        float4 v = ((const float4*)x)[i];
        ushort4 o;
        o.x = f2b(v.x); o.y = f2b(v.y); o.z = f2b(v.z); o.w = f2b(v.w);
        ((ushort4*)Xb)[i] = o;
        return;
    }
    const float* in; u16* out; int N, j;
    if (id < 4864) { j = id - 4096; in = Wa; out = WtA; N = 3072; }
    else           { j = id - 4864; in = Wp; out = WtP; N = 1024; }
    int k0 = (j & 15) * 64, n0 = (j >> 4) * 64;
    int c = t & 63, r0 = t >> 6;
#pragma unroll
    for (int i = 0; i < 16; ++i) {
        int r = r0 + i * 4;
        tile[r][c] = in[(size_t)(k0 + r) * N + n0 + c];
    }
    __syncthreads();
#pragma unroll
    for (int i = 0; i < 16; ++i) {
        int r = r0 + i * 4;
        out[(size_t)(n0 + r) * 1024 + k0 + c] = f2b(tile[c][r]);
    }
}

// =====================================================================
// GEMM core v2 (unchanged from R13/14): C[128x128]/block, dbuf LDS,
// 1 barrier/K-step, XOR-swizzled images.
// =====================================================================
#define GEMM_STAGE(GA0, GA1, GB0, GB1, K, B)                                   \
    do {                                                                       \
        gload_lds16(GA0 + (K), As[B] + tid * 8);                               \
        gload_lds16(GA1 + (K), As[B] + (256 + tid) * 8);                       \
        gload_lds16(GB0 + (K), Bs[B] + tid * 8);                               \
        gload_lds16(GB1 + (K), Bs[B] + (256 + tid) * 8);                       \
    } while (0)

#define GEMM_CORE(Aptr, Bptr)                                                  \
    int tid = threadIdx.x;                                                     \
    int w = tid >> 6, lane = tid & 63, l16 = lane & 15, quad = lane >> 4;      \
    int m0 = blockIdx.x * 128, n0 = blockIdx.y * 128;                          \
    int wr = (w >> 1) * 64, wc = (w & 1) * 64;                                 \
    __shared__ u16 As[2][128 * 32];                                            \
    __shared__ u16 Bs[2][128 * 32];                                            \
    f32x4 acc[4][4];                                                           \
    _Pragma("unroll") for (int mi = 0; mi < 4; ++mi)                           \
        _Pragma("unroll") for (int ni = 0; ni < 4; ++ni)                       \
            _Pragma("unroll") for (int r = 0; r < 4; ++r) acc[mi][ni][r] = 0.f;\
    int srow0 = tid >> 2, srow1 = 64 + srow0;                                  \
    int slc = ((tid & 3) ^ ((tid >> 3) & 3)) * 8;   /* swizzled src chunk */   \
    const u16* gA0 = Aptr + (size_t)(m0 + srow0) * 1024 + slc;                 \
    const u16* gA1 = Aptr + (size_t)(m0 + srow1) * 1024 + slc;                 \
    const u16* gB0 = Bptr + (size_t)(n0 + srow0) * 1024 + slc;                 \
    const u16* gB1 = Bptr + (size_t)(n0 + srow1) * 1024 + slc;                 \
    int cq = (quad ^ ((l16 >> 1) & 3)) * 8;         /* frag phys chunk */      \
    GEMM_STAGE(gA0, gA1, gB0, gB1, 0, 0);                                      \
    for (int it = 0; it < 32; ++it) {                                          \
        int pb = it & 1;                                                       \
        __syncthreads();                  /* drains buf[pb] staging */         \
        bf8 af[4], bf[4];                                                      \
        _Pragma("unroll") for (int mi = 0; mi < 4; ++mi)                       \
            af[mi] = *(const bf8*)(As[pb] + (wr + mi * 16 + l16) * 32 + cq);   \
        _Pragma("unroll") for (int ni = 0; ni < 4; ++ni)                       \
            bf[ni] = *(const bf8*)(Bs[pb] + (wc + ni * 16 + l16) * 32 + cq);   \
        if (it < 31) GEMM_STAGE(gA0, gA1, gB0, gB1, (it + 1) * 32, pb ^ 1);    \
        _Pragma("unroll") for (int mi = 0; mi < 4; ++mi)                       \
            _Pragma("unroll") for (int ni = 0; ni < 4; ++ni)                   \
                acc[mi][ni] = mfma16(af[mi], bf[ni], acc[mi][ni]);             \
    }

// ---------------- QKV GEMM: [4096,1024] @ Wt[3072,1024] + bias ----------------
__global__ __launch_bounds__(256, 3) void k_qkv(const u16* __restrict__ Xb,
                                                const u16* __restrict__ WtA,
                                                const float* __restrict__ ba,
                                                u16* __restrict__ Qb,
                                                u16* __restrict__ Kb,
                                                u16* __restrict__ Vtb) {
    GEMM_CORE(Xb, WtA)
    int sel = n0 >> 10;                       // 0:Q 1:K 2:V (uniform per block)
    u16* dst = sel == 0 ? Qb : (sel == 1 ? Kb : Vtb);
    const float qs = 0.18033688011112042f;    // 0.125 * log2(e)
#pragma unroll
    for (int ni = 0; ni < 4; ++ni) {
        int n = n0 + wc + ni * 16 + l16;
        float bias = ba[n];
        int h = (n & 1023) >> 6;
        int d = n & 63;
#pragma unroll
        for (int mi = 0; mi < 4; ++mi)
#pragma unroll
            for (int r = 0; r < 4; ++r) {
                int m = m0 + wr + mi * 16 + quad * 4 + r;
                int bb = m >> 11, tt = m & 2047;
                float v = acc[mi][ni][r] + bias;
                size_t hb = (size_t)(bb * 16 + h);
                if (sel == 2)                             // V^T tiled
                    dst[hb * 131072 + (size_t)(tt >> 6) * 4096 + d * 64 + (tt & 63)] = f2b(v);
                else
                    dst[(hb * 2048 + tt) * 64 + d] =
                        f2b(sel == 0 ? v * qs : v);
            }
    }
}

// ---------------- proj GEMM: AO[4096,1024] @ WtP[1024,1024] + bias -> fp32 ----------------
__global__ __launch_bounds__(256, 3) void k_proj(const u16* __restrict__ AO,
                                                 const u16* __restrict__ WtP,
                                                 const float* __restrict__ bp,
                                                 float* __restrict__ out) {
    GEMM_CORE(AO, WtP)
#pragma unroll
    for (int ni = 0; ni < 4; ++ni) {
        int n = n0 + wc + ni * 16 + l16;
        float bias = bp[n];
#pragma unroll
        for (int mi = 0; mi < 4; ++mi)
#pragma unroll
            for (int r = 0; r < 4; ++r) {
                int m = m0 + wr + mi * 16 + quad * 4 + r;
                out[(size_t)m * 1024 + n] = acc[mi][ni][r] + bias;
            }
    }
}

// ---------------- flash attention (causal), 32x32 swapped-QK^T, KVBLK=128 ----------------
// Block = 4 waves, one head; wave w owns ONE 32-row q-tile tq = t + 16w.
// Per barrier: stage TWO 64-key tiles (K 16KB contiguous rows; V = two 8KB
// [d][key64] images). All images swizzled phys_chunk = logical ^ (row&7);
// reads XOR by l31&7 -> 8-lane phases hit 8 distinct bank groups (conflict-
// free). Compute per 64-key sub-tile s=0,1 (wave-uniform guards):
//   S^T = mfma32(K,Q^T); exp2 in place (lane-local l_i); P^T repack via
//   v_permlane32_swap_b32 (4 swaps/key-block); O^T += mfma32(V^T, P^T).
// Epilogue: O^T -> O transpose via freed KV LDS, coalesced b128 stores.

#define STAGE128(KT2, B) do {                                                 \
    const u16* kt_ = Kh + (size_t)(KT2) * 8192;                               \
    _Pragma("unroll") for (int i_ = 0; i_ < 4; ++i_) {                        \
        int ci_ = i_ * 256 + tid;            /* 0..1023: 128 rows x 8 chks */ \
        gload_lds16(kt_ + (ci_ >> 3) * 64 +                                   \
                    (((ci_ & 7) ^ ((ci_ >> 3) & 7)) * 8), Ks[B] + ci_ * 8);   \
    }                                                                         \
    const u16* vt_ = Vh + (size_t)(KT2) * 8192;                               \
    _Pragma("unroll") for (int i_ = 0; i_ < 4; ++i_) {                        \
        int ci_ = i_ * 256 + tid;            /* two [64d][64k] images */      \
        gload_lds16(vt_ + (ci_ >> 3) * 64 +                                   \
                    (((ci_ & 7) ^ ((ci_ >> 3) & 7)) * 8), Vs[B] + ci_ * 8);   \
    }                                                                         \
} while (0)

// one PV k-slice SG (keys 16*SG..+15 of the sub-tile); BFR = P^T frag (4 u32)
#define PVSTEP(SG, BFR) do {                                                  \
    bf8 va_ = *(const bf8*)(vb_ + l31 * 64 + (((2 * (SG) + h) ^ swz) * 8));   \
    bf8 vc_ = *(const bf8*)(vb_ + (32 + l31) * 64 +                           \
                            (((2 * (SG) + h) ^ swz) * 8));                    \
    bf8 pf_ = __builtin_bit_cast(bf8, BFR);                                   \
    oT0 = mfma32(va_, pf_, oT0);                                              \
    oT1 = mfma32(vc_, pf_, oT1);                                              \
} while (0)

// pack 32 S^T values -> 8 u32, exchange halves via permlane32_swap: the two
// outputs of each swap are exactly the two B-frag words (R16 BFRAGS mapping).
#define REPACK_PV(ST, SG0, SG1) do {                                          \
    u32 pk_[8];                                                               \
    _Pragma("unroll") for (int j = 0; j < 8; ++j)                             \
        pk_[j] = pk2(ST[2 * j], ST[2 * j + 1]);                               \
    pl32swap(pk_[0], pk_[2]); pl32swap(pk_[1], pk_[3]);                       \
    pl32swap(pk_[4], pk_[6]); pl32swap(pk_[5], pk_[7]);                       \
    u32x4v f0_ = {pk_[0], pk_[1], pk_[2], pk_[3]};                            \
    u32x4v f1_ = {pk_[4], pk_[5], pk_[6], pk_[7]};                            \
    PVSTEP(SG0, f0_);                                                         \
    PVSTEP(SG1, f1_);                                                         \
} while (0)

__global__ __launch_bounds__(256, 2) void k_attn(const u16* __restrict__ Qb,
                                                 const u16* __restrict__ Kb,
                                                 const u16* __restrict__ Vtb,
                                                 u16* __restrict__ AO) {
    // 512 blocks; same-head blocks share id%8 (XCD L2 affinity). Longest first.
    int id = blockIdx.x;                     // 0..511
    int bh = (id & 7) * 4 + ((id >> 3) & 3); // head-batch 0..31
    int t  = 15 - (id >> 5);                 // 0..15
    int tid = threadIdx.x;
    int w = tid >> 6, lane = tid & 63, l31 = lane & 31, h = lane >> 5;

    const u16* Qh = Qb  + (size_t)bh * 131072;
    const u16* Kh = Kb  + (size_t)bh * 131072;
    const u16* Vh = Vtb + (size_t)bh * 131072;      // V^T tiled: [kt][d][t64]

    __shared__ u16 Ks[2][8192];              // [buf][128 key rows x 64 d] 16KB
    __shared__ u16 Vs[2][8192];              // [buf][2 x [64 d][64 key]] 16KB

    int tq = t + 16 * w;                     // q-tile 0..63
    int qr = tq * 32;
    int ktmax = tq >> 1;                     // wave's last 64-key tile
    int nkt = ((t + 48) >> 1) + 1;           // block-uniform 64-key tiles
    int nk2 = (nkt + 1) >> 1;                // 128-key stages (13..16)

    // Q^T fragments (B-operand): lane reads its own q-row, 4 d-slices.
    bf8 qf[4];
#pragma unroll
    for (int s = 0; s < 4; ++s)
        qf[s] = *(const bf8*)(Qh + (size_t)(qr + l31) * 64 + s * 16 + h * 8);

    float l_acc = 0.f;
    f32x16 oT0, oT1;
#pragma unroll
    for (int r = 0; r < 16; ++r) { oT0[r] = 0.f; oT1[r] = 0.f; }

    int swz = l31 & 7;                       // unified read-side XOR selector

    STAGE128(0, 0);
    for (int k2 = 0; k2 < nk2; ++k2) {
        int pb = k2 & 1;
        __syncthreads();                     // drains buf[pb] staging
        if (k2 + 1 < nk2) STAGE128(k2 + 1, pb ^ 1);

#pragma unroll
        for (int s = 0; s < 2; ++s) {
            int kt = 2 * k2 + s;
            if (kt > ktmax) continue;        // wave-uniform
            const u16* kb_ = Ks[pb] + s * 4096;
            const u16* vb_ = Vs[pb] + s * 4096;
            bool diag = (kt == ktmax);
            bool doK1 = !(diag && ((tq & 1) == 0));

            // ---- QK^T: S^T = K · Q^T ----
            f32x16 sT0, sT1;
#pragma unroll
            for (int r = 0; r < 16; ++r) { sT0[r] = 0.f; sT1[r] = 0.f; }
#pragma unroll
            for (int d = 0; d < 4; ++d) {
                bf8 kf = *(const bf8*)(kb_ + l31 * 64 +
                                       (((2 * d + h) ^ swz) * 8));
                sT0 = mfma32(kf, qf[d], sT0);
            }
            if (doK1) {
#pragma unroll
                for (int d = 0; d < 4; ++d) {
                    bf8 kf = *(const bf8*)(kb_ + (32 + l31) * 64 +
                                           (((2 * d + h) ^ swz) * 8));
                    sT1 = mfma32(kf, qf[d], sT1);
                }
            }

            // ---- softmax (exp2, Q pre-scaled; mask only on diag tile) ----
            int kb0 = kt * 64, qg = qr + l31;
            if (diag) {
#pragma unroll
                for (int r = 0; r < 16; ++r) {
                    int krow = kb0 + (r & 3) + 8 * (r >> 2) + 4 * h;
                    sT0[r] = fexp2(krow <= qg ? sT0[r] : -1e30f);
                    l_acc += sT0[r];
                }
                if (doK1) {
#pragma unroll
                    for (int r = 0; r < 16; ++r) {
                        int krow = kb0 + 32 + (r & 3) + 8 * (r >> 2) + 4 * h;
                        sT1[r] = fexp2(krow <= qg ? sT1[r] : -1e30f);
                        l_acc += sT1[r];
                    }
                }
            } else {
#pragma unroll
                for (int r = 0; r < 16; ++r) {
                    sT0[r] = fexp2(sT0[r]); l_acc += sT0[r];
                }
#pragma unroll
                for (int r = 0; r < 16; ++r) {
                    sT1[r] = fexp2(sT1[r]); l_acc += sT1[r];
                }
            }

            // ---- P^T repack (permlane32_swap) + PV ----
            REPACK_PV(sT0, 0, 1);
            if (doK1) REPACK_PV(sT1, 2, 3);
        }
    }

    // ---- epilogue: normalize, transpose O^T -> O via freed KV LDS ----
    __syncthreads();                         // all waves done reading KV
    float lsum = l_acc + __shfl_xor(l_acc, 32, 64);
    float linv = __builtin_amdgcn_rcpf(lsum);

    u32* Ot = (u32*)(&Ks[0][0]) + w * 1152;  // [32 q][36-pad u32 cols]
#pragma unroll
    for (int j = 0; j < 8; ++j) {
        int col = 4 * (j >> 1) + 2 * h + (j & 1);   // d/2 within 32-block
        Ot[l31 * 36 + col]      = pk2(oT0[2 * j] * linv, oT0[2 * j + 1] * linv);
        Ot[l31 * 36 + 16 + col] = pk2(oT1[2 * j] * linv, oT1[2 * j + 1] * linv);
    }
    asm volatile("s_waitcnt lgkmcnt(0)" ::: "memory");
    __builtin_amdgcn_sched_barrier(0);       // rule #18: pin reads after fence

    int q2 = lane >> 1, half = lane & 1;
    int eb = bh >> 4, eh = bh & 15;
    size_t row = (size_t)eb * 2048 + qr + q2;
    const u32* src = Ot + q2 * 36 + half * 16;
    u32* dstg = (u32*)(AO + row * 1024 + eh * 64) + half * 16;
#pragma unroll
    for (int c = 0; c < 4; ++c)
        *(u32x4v*)(dstg + 4 * c) = *(const u32x4v*)(src + 4 * c);
}

extern "C" void kernel_launch(void* const* d_in, const int* in_sizes, int n_in,
                              void* d_out, int out_size, void* d_ws, size_t ws_size,
                              hipStream_t stream) {
    const float* x  = (const float*)d_in[0];
    const float* Wa = (const float*)d_in[1];
    const float* ba = (const float*)d_in[2];
    const float* Wp = (const float*)d_in[3];
    const float* bp = (const float*)d_in[4];
    float* out = (float*)d_out;

    char* ws = (char*)d_ws;
    const size_t MB = 1024 * 1024;
    u16* Xb  = (u16*)(ws);             // 8 MB  x as bf16   (reused as AO later)
    u16* WtA = (u16*)(ws + 8  * MB);   // 6 MB  W_attn^T bf16
    u16* WtP = (u16*)(ws + 14 * MB);   // 2 MB  W_proj^T bf16
    u16* Qb  = (u16*)(ws + 16 * MB);   // 8 MB  [B*H][T][D], pre-scaled
    u16* Kb  = (u16*)(ws + 24 * MB);   // 8 MB  [B*H][T][D]
    u16* Vtb = (u16*)(ws + 32 * MB);   // 8 MB  [B*H][32][64][64] tiled V^T
    u16* AO  = Xb;                     // alias: Xb dead after k_qkv (stream-ordered)

    k_prep<<<dim3(5120),    dim3(256), 0, stream>>>(x, Wa, Wp, Xb, WtA, WtP);
    k_qkv <<<dim3(32, 24),  dim3(256), 0, stream>>>(Xb, WtA, ba, Qb, Kb, Vtb);
    k_attn<<<dim3(512),     dim3(256), 0, stream>>>(Qb, Kb, Vtb, AO);
    k_proj<<<dim3(32, 8),   dim3(256), 0, stream>>>(AO, WtP, bp, out);
}

// Round 8
// 174.098 us; speedup vs baseline: 1.1299x; 1.0190x over previous
//
#include <hip/hip_runtime.h>

// Fused causal self-attention block, MI355X gfx950.
// B=2, T=2048, E=1024, H=16, D=64.
// Verified 16x16x32 layouts (m89/m91): A[m=lane&15][k=(lane>>4)*8+j],
//   B[k=(lane>>4)*8+j][n=lane&15], C/D[row=(lane>>4)*4+r][col=lane&15].
// 32x32x16 layouts (m74/m101): A[m=lane&31][k=(lane>>5)*8+j],
//   B[k=(lane>>5)*8+j][n=lane&31], C/D[col=lane&31, row=(reg&3)+8*(reg>>2)+4*(lane>>5)].
// R12 FAILED: per-lane global K/V frag loads = L1 transaction-bound; keep
//   global_load_lds staging.
// R13/14 (landed, attn ~41us): 16x16 + swizzled P LDS + native-cast f2b.
// R15 FAILED (65us): 1 wave/SIMD latency-bound. Need >=2 waves/SIMD.
// R16 (50.5us): 32x32 swapped-QK^T, in-register P repack (verified).
// R17 (44.5us): permlane32_swap repack + KVBLK=128. Post-mortem: conflicts
//   IDENTICAL to R16 (2228224) -> frag reads were never the source (~2% cost,
//   epilogue). Real hole: tq = t+16w gives wave 0 ktmax=t/2 but block loops
//   to (t+48)/2 -> ~43% of wave-slots idle at barriers (matches 57% no-issue
//   from MfmaUtil 14 + VALUBusy 28.5).
// R18 (this round): wave->tile remap tq = 4t+w -> ktmax = 2t+(w>>1), equal
//   across waves +-1; idle 43% -> ~3%. Block loop nk2 = t+1. Hand-treed
//   l_acc sum (kills 32-deep dependent add chain). Everything else identical.

typedef unsigned short u16;
typedef unsigned int u32;
typedef __bf16 bf8 __attribute__((ext_vector_type(8)));
typedef float f32x4 __attribute__((ext_vector_type(4)));
typedef float f32x16 __attribute__((ext_vector_type(16)));
typedef u32 u32x4v __attribute__((ext_vector_type(4)));

__device__ __forceinline__ u16 f2b(float f) {
    return __builtin_bit_cast(u16, (__bf16)f);         // RNE
}

__device__ __forceinline__ u32 pk2(float lo, float hi) {
    return (u32)f2b(lo) | ((u32)f2b(hi) << 16);
}

__device__ __forceinline__ f32x4 mfma16(bf8 a, bf8 b, f32x4 c) {
    return __builtin_amdgcn_mfma_f32_16x16x32_bf16(a, b, c, 0, 0, 0);
}

__device__ __forceinline__ f32x16 mfma32(bf8 a, bf8 b, f32x16 c) {
    return __builtin_amdgcn_mfma_f32_32x32x16_bf16(a, b, c, 0, 0, 0);
}

__device__ __forceinline__ float fexp2(float x) {
    return __builtin_amdgcn_exp2f(x);                  // v_exp_f32
}

// a' = [a.lo31, b.lo31]; b' = [a.hi31, b.hi31]  (VALU cross-half exchange)
__device__ __forceinline__ void pl32swap(u32& a, u32& b) {
    asm("v_permlane32_swap_b32 %0, %1" : "+v"(a), "+v"(b));
}

// async global->LDS, 16B per lane. LDS dest must be wave-uniform base + lane*16.
__device__ __forceinline__ void gload_lds16(const u16* g, u16* l) {
    __builtin_amdgcn_global_load_lds(
        (__attribute__((address_space(1))) void*)(g),
        (__attribute__((address_space(3))) void*)(l), 16, 0, 0);
}

// ---------------- prep: x->bf16 convert + both weight transposes ----------------
__global__ __launch_bounds__(256) void k_prep(const float* __restrict__ x,
                                              const float* __restrict__ Wa,
                                              const float* __restrict__ Wp,
                                              u16* __restrict__ Xb,
                                              u16* __restrict__ WtA,
                                              u16* __restrict__ WtP) {
    __shared__ float tile[64][65];
    int id = blockIdx.x, t = threadIdx.x;
    if (id < 4096) {                         // convert 4 floats/thread
        int i = id * 256 + t;
        float4 v = ((const float4*)x)[i];
        ushort4 o;
        o.x = f2b(v.x); o.y = f2b(v.y); o.z = f2b(v.z); o.w = f2b(v.w);
        ((ushort4*)Xb)[i] = o;
        return;
    }
    const float* in; u16* out; int N, j;
    if (id < 4864) { j = id - 4096; in = Wa; out = WtA; N = 3072; }
    else           { j = id - 4864; in = Wp; out = WtP; N = 1024; }
    int k0 = (j & 15) * 64, n0 = (j >> 4) * 64;
    int c = t & 63, r0 = t >> 6;
#pragma unroll
    for (int i = 0; i < 16; ++i) {
        int r = r0 + i * 4;
        tile[r][c] = in[(size_t)(k0 + r) * N + n0 + c];
    }
    __syncthreads();
#pragma unroll
    for (int i = 0; i < 16; ++i) {
        int r = r0 + i * 4;
        out[(size_t)(n0 + r) * 1024 + k0 + c] = f2b(tile[c][r]);
    }
}

// =====================================================================
// GEMM core v2 (unchanged from R13/14): C[128x128]/block, dbuf LDS,
// 1 barrier/K-step, XOR-swizzled images.
// =====================================================================
#define GEMM_STAGE(GA0, GA1, GB0, GB1, K, B)                                   \
    do {                                                                       \
        gload_lds16(GA0 + (K), As[B] + tid * 8);                               \
        gload_lds16(GA1 + (K), As[B] + (256 + tid) * 8);                       \
        gload_lds16(GB0 + (K), Bs[B] + tid * 8);                               \
        gload_lds16(GB1 + (K), Bs[B] + (256 + tid) * 8);                       \
    } while (0)

#define GEMM_CORE(Aptr, Bptr)                                                  \
    int tid = threadIdx.x;                                                     \
    int w = tid >> 6, lane = tid & 63, l16 = lane & 15, quad = lane >> 4;      \
    int m0 = blockIdx.x * 128, n0 = blockIdx.y * 128;                          \
    int wr = (w >> 1) * 64, wc = (w & 1) * 64;                                 \
    __shared__ u16 As[2][128 * 32];                                            \
    __shared__ u16 Bs[2][128 * 32];                                            \
    f32x4 acc[4][4];                                                           \
    _Pragma("unroll") for (int mi = 0; mi < 4; ++mi)                           \
        _Pragma("unroll") for (int ni = 0; ni < 4; ++ni)                       \
            _Pragma("unroll") for (int r = 0; r < 4; ++r) acc[mi][ni][r] = 0.f;\
    int srow0 = tid >> 2, srow1 = 64 + srow0;                                  \
    int slc = ((tid & 3) ^ ((tid >> 3) & 3)) * 8;   /* swizzled src chunk */   \
    const u16* gA0 = Aptr + (size_t)(m0 + srow0) * 1024 + slc;                 \
    const u16* gA1 = Aptr + (size_t)(m0 + srow1) * 1024 + slc;                 \
    const u16* gB0 = Bptr + (size_t)(n0 + srow0) * 1024 + slc;                 \
    const u16* gB1 = Bptr + (size_t)(n0 + srow1) * 1024 + slc;                 \
    int cq = (quad ^ ((l16 >> 1) & 3)) * 8;         /* frag phys chunk */      \
    GEMM_STAGE(gA0, gA1, gB0, gB1, 0, 0);                                      \
    for (int it = 0; it < 32; ++it) {                                          \
        int pb = it & 1;                                                       \
        __syncthreads();                  /* drains buf[pb] staging */         \
        bf8 af[4], bf[4];                                                      \
        _Pragma("unroll") for (int mi = 0; mi < 4; ++mi)                       \
            af[mi] = *(const bf8*)(As[pb] + (wr + mi * 16 + l16) * 32 + cq);   \
        _Pragma("unroll") for (int ni = 0; ni < 4; ++ni)                       \
            bf[ni] = *(const bf8*)(Bs[pb] + (wc + ni * 16 + l16) * 32 + cq);   \
        if (it < 31) GEMM_STAGE(gA0, gA1, gB0, gB1, (it + 1) * 32, pb ^ 1);    \
        _Pragma("unroll") for (int mi = 0; mi < 4; ++mi)                       \
            _Pragma("unroll") for (int ni = 0; ni < 4; ++ni)                   \
                acc[mi][ni] = mfma16(af[mi], bf[ni], acc[mi][ni]);             \
    }

// ---------------- QKV GEMM: [4096,1024] @ Wt[3072,1024] + bias ----------------
__global__ __launch_bounds__(256, 3) void k_qkv(const u16* __restrict__ Xb,
                                                const u16* __restrict__ WtA,
                                                const float* __restrict__ ba,
                                                u16* __restrict__ Qb,
                                                u16* __restrict__ Kb,
                                                u16* __restrict__ Vtb) {
    GEMM_CORE(Xb, WtA)
    int sel = n0 >> 10;                       // 0:Q 1:K 2:V (uniform per block)
    u16* dst = sel == 0 ? Qb : (sel == 1 ? Kb : Vtb);
    const float qs = 0.18033688011112042f;    // 0.125 * log2(e)
#pragma unroll
    for (int ni = 0; ni < 4; ++ni) {
        int n = n0 + wc + ni * 16 + l16;
        float bias = ba[n];
        int h = (n & 1023) >> 6;
        int d = n & 63;
#pragma unroll
        for (int mi = 0; mi < 4; ++mi)
#pragma unroll
            for (int r = 0; r < 4; ++r) {
                int m = m0 + wr + mi * 16 + quad * 4 + r;
                int bb = m >> 11, tt = m & 2047;
                float v = acc[mi][ni][r] + bias;
                size_t hb = (size_t)(bb * 16 + h);
                if (sel == 2)                             // V^T tiled
                    dst[hb * 131072 + (size_t)(tt >> 6) * 4096 + d * 64 + (tt & 63)] = f2b(v);
                else
                    dst[(hb * 2048 + tt) * 64 + d] =
                        f2b(sel == 0 ? v * qs : v);
            }
    }
}

// ---------------- proj GEMM: AO[4096,1024] @ WtP[1024,1024] + bias -> fp32 ----------------
__global__ __launch_bounds__(256, 3) void k_proj(const u16* __restrict__ AO,
                                                 const u16* __restrict__ WtP,
                                                 const float* __restrict__ bp,
                                                 float* __restrict__ out) {
    GEMM_CORE(AO, WtP)
#pragma unroll
    for (int ni = 0; ni < 4; ++ni) {
        int n = n0 + wc + ni * 16 + l16;
        float bias = bp[n];
#pragma unroll
        for (int mi = 0; mi < 4; ++mi)
#pragma unroll
            for (int r = 0; r < 4; ++r) {
                int m = m0 + wr + mi * 16 + quad * 4 + r;
                out[(size_t)m * 1024 + n] = acc[mi][ni][r] + bias;
            }
    }
}

// ---------------- flash attention (causal), 32x32 swapped-QK^T, KVBLK=128 ----------------
// Block = 4 waves, one head; wave w owns q-tile tq = 4t + w (ADJACENT tiles:
// ktmax = 2t + (w>>1), equal across waves +-1 -> ~3% barrier idle, was 43%).
// Per barrier: stage TWO 64-key tiles. Images swizzled phys_chunk =
// logical ^ (row&7); reads XOR by l31&7. Compute per 64-key sub-tile
// (wave-uniform guards): S^T = mfma32(K,Q^T); exp2 (lane-local l_i, treed
// sum); P^T repack via v_permlane32_swap_b32; O^T += mfma32(V^T, P^T).
// Epilogue: O^T -> O transpose via freed KV LDS, coalesced b128 stores.

#define STAGE128(KT2, B) do {                                                 \
    const u16* kt_ = Kh + (size_t)(KT2) * 8192;                               \
    _Pragma("unroll") for (int i_ = 0; i_ < 4; ++i_) {                        \
        int ci_ = i_ * 256 + tid;            /* 0..1023: 128 rows x 8 chks */ \
        gload_lds16(kt_ + (ci_ >> 3) * 64 +                                   \
                    (((ci_ & 7) ^ ((ci_ >> 3) & 7)) * 8), Ks[B] + ci_ * 8);   \
    }                                                                         \
    const u16* vt_ = Vh + (size_t)(KT2) * 8192;                               \
    _Pragma("unroll") for (int i_ = 0; i_ < 4; ++i_) {                        \
        int ci_ = i_ * 256 + tid;            /* two [64d][64k] images */      \
        gload_lds16(vt_ + (ci_ >> 3) * 64 +                                   \
                    (((ci_ & 7) ^ ((ci_ >> 3) & 7)) * 8), Vs[B] + ci_ * 8);   \
    }                                                                         \
} while (0)

// one PV k-slice SG (keys 16*SG..+15 of the sub-tile); BFR = P^T frag (4 u32)
#define PVSTEP(SG, BFR) do {                                                  \
    bf8 va_ = *(const bf8*)(vb_ + l31 * 64 + (((2 * (SG) + h) ^ swz) * 8));   \
    bf8 vc_ = *(const bf8*)(vb_ + (32 + l31) * 64 +                           \
                            (((2 * (SG) + h) ^ swz) * 8));                    \
    bf8 pf_ = __builtin_bit_cast(bf8, BFR);                                   \
    oT0 = mfma32(va_, pf_, oT0);                                              \
    oT1 = mfma32(vc_, pf_, oT1);                                              \
} while (0)

// pack 32 S^T values -> 8 u32, exchange halves via permlane32_swap: the two
// outputs of each swap are exactly the two B-frag words (R16 BFRAGS mapping).
#define REPACK_PV(ST, SG0, SG1) do {                                          \
    u32 pk_[8];                                                               \
    _Pragma("unroll") for (int j = 0; j < 8; ++j)                             \
        pk_[j] = pk2(ST[2 * j], ST[2 * j + 1]);                               \
    pl32swap(pk_[0], pk_[2]); pl32swap(pk_[1], pk_[3]);                       \
    pl32swap(pk_[4], pk_[6]); pl32swap(pk_[5], pk_[7]);                       \
    u32x4v f0_ = {pk_[0], pk_[1], pk_[2], pk_[3]};                            \
    u32x4v f1_ = {pk_[4], pk_[5], pk_[6], pk_[7]};                            \
    PVSTEP(SG0, f0_);                                                         \
    PVSTEP(SG1, f1_);                                                         \
} while (0)

// balanced tree sum of 16 floats (no 16-deep serial chain)
#define TREE16(S)                                                             \
    (((((S)[0] + (S)[1]) + ((S)[2] + (S)[3])) +                               \
      (((S)[4] + (S)[5]) + ((S)[6] + (S)[7]))) +                              \
     ((((S)[8] + (S)[9]) + ((S)[10] + (S)[11])) +                             \
      (((S)[12] + (S)[13]) + ((S)[14] + (S)[15]))))

__global__ __launch_bounds__(256, 2) void k_attn(const u16* __restrict__ Qb,
                                                 const u16* __restrict__ Kb,
                                                 const u16* __restrict__ Vtb,
                                                 u16* __restrict__ AO) {
    // 512 blocks; same-head blocks share id%8 (XCD L2 affinity). Longest first.
    int id = blockIdx.x;                     // 0..511
    int bh = (id & 7) * 4 + ((id >> 3) & 3); // head-batch 0..31
    int t  = 15 - (id >> 5);                 // 0..15
    int tid = threadIdx.x;
    int w = tid >> 6, lane = tid & 63, l31 = lane & 31, h = lane >> 5;

    const u16* Qh = Qb  + (size_t)bh * 131072;
    const u16* Kh = Kb  + (size_t)bh * 131072;
    const u16* Vh = Vtb + (size_t)bh * 131072;      // V^T tiled: [kt][d][t64]

    __shared__ u16 Ks[2][8192];              // [buf][128 key rows x 64 d] 16KB
    __shared__ u16 Vs[2][8192];              // [buf][2 x [64 d][64 key]] 16KB

    int tq = 4 * t + w;                      // ADJACENT tiles: equal ktmax +-1
    int qr = tq * 32;
    int ktmax = tq >> 1;                     // wave's last 64-key tile
    int nk2 = t + 1;                         // block-uniform 128-key stages

    // Q^T fragments (B-operand): lane reads its own q-row, 4 d-slices.
    bf8 qf[4];
#pragma unroll
    for (int s = 0; s < 4; ++s)
        qf[s] = *(const bf8*)(Qh + (size_t)(qr + l31) * 64 + s * 16 + h * 8);

    float l_acc = 0.f;
    f32x16 oT0, oT1;
#pragma unroll
    for (int r = 0; r < 16; ++r) { oT0[r] = 0.f; oT1[r] = 0.f; }

    int swz = l31 & 7;                       // unified read-side XOR selector

    STAGE128(0, 0);
    for (int k2 = 0; k2 < nk2; ++k2) {
        int pb = k2 & 1;
        __syncthreads();                     // drains buf[pb] staging
        if (k2 + 1 < nk2) STAGE128(k2 + 1, pb ^ 1);

#pragma unroll
        for (int s = 0; s < 2; ++s) {
            int kt = 2 * k2 + s;
            if (kt > ktmax) continue;        // wave-uniform
            const u16* kb_ = Ks[pb] + s * 4096;
            const u16* vb_ = Vs[pb] + s * 4096;
            bool diag = (kt == ktmax);
            bool doK1 = !(diag && ((tq & 1) == 0));

            // ---- QK^T: S^T = K · Q^T ----
            f32x16 sT0, sT1;
#pragma unroll
            for (int r = 0; r < 16; ++r) { sT0[r] = 0.f; sT1[r] = 0.f; }
#pragma unroll
            for (int d = 0; d < 4; ++d) {
                bf8 kf = *(const bf8*)(kb_ + l31 * 64 +
                                       (((2 * d + h) ^ swz) * 8));
                sT0 = mfma32(kf, qf[d], sT0);
            }
            if (doK1) {
#pragma unroll
                for (int d = 0; d < 4; ++d) {
                    bf8 kf = *(const bf8*)(kb_ + (32 + l31) * 64 +
                                           (((2 * d + h) ^ swz) * 8));
                    sT1 = mfma32(kf, qf[d], sT1);
                }
            }

            // ---- softmax (exp2, Q pre-scaled; mask only on diag tile) ----
            int kb0 = kt * 64, qg = qr + l31;
            if (diag) {
#pragma unroll
                for (int r = 0; r < 16; ++r) {
                    int krow = kb0 + (r & 3) + 8 * (r >> 2) + 4 * h;
                    sT0[r] = fexp2(krow <= qg ? sT0[r] : -1e30f);
                }
                if (doK1) {
#pragma unroll
                    for (int r = 0; r < 16; ++r) {
                        int krow = kb0 + 32 + (r & 3) + 8 * (r >> 2) + 4 * h;
                        sT1[r] = fexp2(krow <= qg ? sT1[r] : -1e30f);
                    }
                }
            } else {
#pragma unroll
                for (int r = 0; r < 16; ++r) sT0[r] = fexp2(sT0[r]);
#pragma unroll
                for (int r = 0; r < 16; ++r) sT1[r] = fexp2(sT1[r]);
            }
            l_acc += TREE16(sT0);
            if (doK1) l_acc += TREE16(sT1);

            // ---- P^T repack (permlane32_swap) + PV ----
            REPACK_PV(sT0, 0, 1);
            if (doK1) REPACK_PV(sT1, 2, 3);
        }
    }

    // ---- epilogue: normalize, transpose O^T -> O via freed KV LDS ----
    __syncthreads();                         // all waves done reading KV
    float lsum = l_acc + __shfl_xor(l_acc, 32, 64);
    float linv = __builtin_amdgcn_rcpf(lsum);

    u32* Ot = (u32*)(&Ks[0][0]) + w * 1152;  // [32 q][36-pad u32 cols]
#pragma unroll
    for (int j = 0; j < 8; ++j) {
        int col = 4 * (j >> 1) + 2 * h + (j & 1);   // d/2 within 32-block
        Ot[l31 * 36 + col]      = pk2(oT0[2 * j] * linv, oT0[2 * j + 1] * linv);
        Ot[l31 * 36 + 16 + col] = pk2(oT1[2 * j] * linv, oT1[2 * j + 1] * linv);
    }
    asm volatile("s_waitcnt lgkmcnt(0)" ::: "memory");
    __builtin_amdgcn_sched_barrier(0);       // rule #18: pin reads after fence

    int q2 = lane >> 1, half = lane & 1;
    int eb = bh >> 4, eh = bh & 15;
    size_t row = (size_t)eb * 2048 + qr + q2;
    const u32* src = Ot + q2 * 36 + half * 16;
    u32* dstg = (u32*)(AO + row * 1024 + eh * 64) + half * 16;
#pragma unroll
    for (int c = 0; c < 4; ++c)
        *(u32x4v*)(dstg + 4 * c) = *(const u32x4v*)(src + 4 * c);
}

extern "C" void kernel_launch(void* const* d_in, const int* in_sizes, int n_in,
                              void* d_out, int out_size, void* d_ws, size_t ws_size,
                              hipStream_t stream) {
    const float* x  = (const float*)d_in[0];
    const float* Wa = (const float*)d_in[1];
    const float* ba = (const float*)d_in[2];
    const float* Wp = (const float*)d_in[3];
    const float* bp = (const float*)d_in[4];
    float* out = (float*)d_out;

    char* ws = (char*)d_ws;
    const size_t MB = 1024 * 1024;
    u16* Xb  = (u16*)(ws);             // 8 MB  x as bf16   (reused as AO later)
    u16* WtA = (u16*)(ws + 8  * MB);   // 6 MB  W_attn^T bf16
    u16* WtP = (u16*)(ws + 14 * MB);   // 2 MB  W_proj^T bf16
    u16* Qb  = (u16*)(ws + 16 * MB);   // 8 MB  [B*H][T][D], pre-scaled
    u16* Kb  = (u16*)(ws + 24 * MB);   // 8 MB  [B*H][T][D]
    u16* Vtb = (u16*)(ws + 32 * MB);   // 8 MB  [B*H][32][64][64] tiled V^T
    u16* AO  = Xb;                     // alias: Xb dead after k_qkv (stream-ordered)

    k_prep<<<dim3(5120),    dim3(256), 0, stream>>>(x, Wa, Wp, Xb, WtA, WtP);
    k_qkv <<<dim3(32, 24),  dim3(256), 0, stream>>>(Xb, WtA, ba, Qb, Kb, Vtb);
    k_attn<<<dim3(512),     dim3(256), 0, stream>>>(Qb, Kb, Vtb, AO);
    k_proj<<<dim3(32, 8),   dim3(256), 0, stream>>>(AO, WtP, bp, out);
}

// Round 10
// 172.717 us; speedup vs baseline: 1.1390x; 1.0080x over previous
//
#include <hip/hip_runtime.h>

// Fused causal self-attention block, MI355X gfx950.
// B=2, T=2048, E=1024, H=16, D=64.
// 32x32x16 layouts (m74/m101): A[m=lane&31][k=(lane>>5)*8+j],
//   B[k=(lane>>5)*8+j][n=lane&31], C/D[col=lane&31, row=(reg&3)+8*(reg>>2)+4*(lane>>5)].
// R12 FAILED: per-lane global K/V frag loads = L1 transaction-bound; keep
//   global_load_lds staging.
// R13/14 (landed, attn ~41us): 16x16 + swizzled P LDS + native-cast f2b.
// R15 FAILED (65us): 1 wave/SIMD latency-bound. Need >=2 waves/SIMD.
// R16 (50.5us): 32x32 swapped-QK^T, in-register P repack (verified).
// R17 (44.5us): permlane32_swap repack + KVBLK=128.
// R18 (~41us, total 174.1): wave->tile remap equalized ktmax; only +3us --
//   co-resident block already covered barrier idle. ANALYSIS: non-attn dur is
//   a constant ~132us = ~90us harness fillBuffer (2x268MB workspace poison,
//   inside the timed region) + ~42us for prep/qkv/proj. k_attn (~41us) is
//   half the controllable budget. Stall = 2 waves/SIMD phase-aligned by the
//   stage barrier (57% no-issue; dependent 4-deep MFMA chains + VALU bursts).
// R19: SPLIT-K attention. 8-wave blocks (512 thr): wave w -> q-tile
//   tq=4t+(w&3), key parity p=w>>2 processes kt===p (mod 2). Same staging/
//   barriers, half work per wave per stage -> 4096 waves, 16/CU, 4/SIMD: two
//   independent chains per pipe per phase. Softmax has no running max ->
//   exact combine: partner adds (O^T,l) via LDS once at the end.
//   (R19 bench hit the container-acquisition flake -- same signature as
//   R13/R14 which passed unchanged on resubmit. Audited for deadlock/OOB:
//   uniform barriers, LDS regions disjoint, bounds checked. Resubmitted
//   byte-identical as R20.)

typedef unsigned short u16;
typedef unsigned int u32;
typedef __bf16 bf8 __attribute__((ext_vector_type(8)));
typedef float f32x4 __attribute__((ext_vector_type(4)));
typedef float f32x16 __attribute__((ext_vector_type(16)));
typedef u32 u32x4v __attribute__((ext_vector_type(4)));

__device__ __forceinline__ u16 f2b(float f) {
    return __builtin_bit_cast(u16, (__bf16)f);         // RNE
}

__device__ __forceinline__ u32 pk2(float lo, float hi) {
    return (u32)f2b(lo) | ((u32)f2b(hi) << 16);
}

__device__ __forceinline__ f32x4 mfma16(bf8 a, bf8 b, f32x4 c) {
    return __builtin_amdgcn_mfma_f32_16x16x32_bf16(a, b, c, 0, 0, 0);
}

__device__ __forceinline__ f32x16 mfma32(bf8 a, bf8 b, f32x16 c) {
    return __builtin_amdgcn_mfma_f32_32x32x16_bf16(a, b, c, 0, 0, 0);
}

__device__ __forceinline__ float fexp2(float x) {
    return __builtin_amdgcn_exp2f(x);                  // v_exp_f32
}

// a' = [a.lo31, b.lo31]; b' = [a.hi31, b.hi31]  (VALU cross-half exchange)
__device__ __forceinline__ void pl32swap(u32& a, u32& b) {
    asm("v_permlane32_swap_b32 %0, %1" : "+v"(a), "+v"(b));
}

// async global->LDS, 16B per lane. LDS dest must be wave-uniform base + lane*16.
__device__ __forceinline__ void gload_lds16(const u16* g, u16* l) {
    __builtin_amdgcn_global_load_lds(
        (__attribute__((address_space(1))) void*)(g),
        (__attribute__((address_space(3))) void*)(l), 16, 0, 0);
}

// ---------------- prep: x->bf16 convert + both weight transposes ----------------
__global__ __launch_bounds__(256) void k_prep(const float* __restrict__ x,
                                              const float* __restrict__ Wa,
                                              const float* __restrict__ Wp,
                                              u16* __restrict__ Xb,
                                              u16* __restrict__ WtA,
                                              u16* __restrict__ WtP) {
    __shared__ float tile[64][65];
    int id = blockIdx.x, t = threadIdx.x;
    if (id < 4096) {                         // convert 4 floats/thread
        int i = id * 256 + t;
        float4 v = ((const float4*)x)[i];
        ushort4 o;
        o.x = f2b(v.x); o.y = f2b(v.y); o.z = f2b(v.z); o.w = f2b(v.w);
        ((ushort4*)Xb)[i] = o;
        return;
    }
    const float* in; u16* out; int N, j;
    if (id < 4864) { j = id - 4096; in = Wa; out = WtA; N = 3072; }
    else           { j = id - 4864; in = Wp; out = WtP; N = 1024; }
    int k0 = (j & 15) * 64, n0 = (j >> 4) * 64;
    int c = t & 63, r0 = t >> 6;
#pragma unroll
    for (int i = 0; i < 16; ++i) {
        int r = r0 + i * 4;
        tile[r][c] = in[(size_t)(k0 + r) * N + n0 + c];
    }
    __syncthreads();
#pragma unroll
    for (int i = 0; i < 16; ++i) {
        int r = r0 + i * 4;
        out[(size_t)(n0 + r) * 1024 + k0 + c] = f2b(tile[c][r]);
    }
}

// =====================================================================
// GEMM core v2 (unchanged from R13/14): C[128x128]/block, dbuf LDS,
// 1 barrier/K-step, XOR-swizzled images.
// =====================================================================
#define GEMM_STAGE(GA0, GA1, GB0, GB1, K, B)                                   \
    do {                                                                       \
        gload_lds16(GA0 + (K), As[B] + tid * 8);                               \
        gload_lds16(GA1 + (K), As[B] + (256 + tid) * 8);                       \
        gload_lds16(GB0 + (K), Bs[B] + tid * 8);                               \
        gload_lds16(GB1 + (K), Bs[B] + (256 + tid) * 8);                       \
    } while (0)

#define GEMM_CORE(Aptr, Bptr)                                                  \
    int tid = threadIdx.x;                                                     \
    int w = tid >> 6, lane = tid & 63, l16 = lane & 15, quad = lane >> 4;      \
    int m0 = blockIdx.x * 128, n0 = blockIdx.y * 128;                          \
    int wr = (w >> 1) * 64, wc = (w & 1) * 64;                                 \
    __shared__ u16 As[2][128 * 32];                                            \
    __shared__ u16 Bs[2][128 * 32];                                            \
    f32x4 acc[4][4];                                                           \
    _Pragma("unroll") for (int mi = 0; mi < 4; ++mi)                           \
        _Pragma("unroll") for (int ni = 0; ni < 4; ++ni)                       \
            _Pragma("unroll") for (int r = 0; r < 4; ++r) acc[mi][ni][r] = 0.f;\
    int srow0 = tid >> 2, srow1 = 64 + srow0;                                  \
    int slc = ((tid & 3) ^ ((tid >> 3) & 3)) * 8;   /* swizzled src chunk */   \
    const u16* gA0 = Aptr + (size_t)(m0 + srow0) * 1024 + slc;                 \
    const u16* gA1 = Aptr + (size_t)(m0 + srow1) * 1024 + slc;                 \
    const u16* gB0 = Bptr + (size_t)(n0 + srow0) * 1024 + slc;                 \
    const u16* gB1 = Bptr + (size_t)(n0 + srow1) * 1024 + slc;                 \
    int cq = (quad ^ ((l16 >> 1) & 3)) * 8;         /* frag phys chunk */      \
    GEMM_STAGE(gA0, gA1, gB0, gB1, 0, 0);                                      \
    for (int it = 0; it < 32; ++it) {                                          \
        int pb = it & 1;                                                       \
        __syncthreads();                  /* drains buf[pb] staging */         \
        bf8 af[4], bf[4];                                                      \
        _Pragma("unroll") for (int mi = 0; mi < 4; ++mi)                       \
            af[mi] = *(const bf8*)(As[pb] + (wr + mi * 16 + l16) * 32 + cq);   \
        _Pragma("unroll") for (int ni = 0; ni < 4; ++ni)                       \
            bf[ni] = *(const bf8*)(Bs[pb] + (wc + ni * 16 + l16) * 32 + cq);   \
        if (it < 31) GEMM_STAGE(gA0, gA1, gB0, gB1, (it + 1) * 32, pb ^ 1);    \
        _Pragma("unroll") for (int mi = 0; mi < 4; ++mi)                       \
            _Pragma("unroll") for (int ni = 0; ni < 4; ++ni)                   \
                acc[mi][ni] = mfma16(af[mi], bf[ni], acc[mi][ni]);             \
    }

// ---------------- QKV GEMM: [4096,1024] @ Wt[3072,1024] + bias ----------------
__global__ __launch_bounds__(256, 3) void k_qkv(const u16* __restrict__ Xb,
                                                const u16* __restrict__ WtA,
                                                const float* __restrict__ ba,
                                                u16* __restrict__ Qb,
                                                u16* __restrict__ Kb,
                                                u16* __restrict__ Vtb) {
    GEMM_CORE(Xb, WtA)
    int sel = n0 >> 10;                       // 0:Q 1:K 2:V (uniform per block)
    u16* dst = sel == 0 ? Qb : (sel == 1 ? Kb : Vtb);
    const float qs = 0.18033688011112042f;    // 0.125 * log2(e)
#pragma unroll
    for (int ni = 0; ni < 4; ++ni) {
        int n = n0 + wc + ni * 16 + l16;
        float bias = ba[n];
        int h = (n & 1023) >> 6;
        int d = n & 63;
#pragma unroll
        for (int mi = 0; mi < 4; ++mi)
#pragma unroll
            for (int r = 0; r < 4; ++r) {
                int m = m0 + wr + mi * 16 + quad * 4 + r;
                int bb = m >> 11, tt = m & 2047;
                float v = acc[mi][ni][r] + bias;
                size_t hb = (size_t)(bb * 16 + h);
                if (sel == 2)                             // V^T tiled
                    dst[hb * 131072 + (size_t)(tt >> 6) * 4096 + d * 64 + (tt & 63)] = f2b(v);
                else
                    dst[(hb * 2048 + tt) * 64 + d] =
                        f2b(sel == 0 ? v * qs : v);
            }
    }
}

// ---------------- proj GEMM: AO[4096,1024] @ WtP[1024,1024] + bias -> fp32 ----------------
__global__ __launch_bounds__(256, 3) void k_proj(const u16* __restrict__ AO,
                                                 const u16* __restrict__ WtP,
                                                 const float* __restrict__ bp,
                                                 float* __restrict__ out) {
    GEMM_CORE(AO, WtP)
#pragma unroll
    for (int ni = 0; ni < 4; ++ni) {
        int n = n0 + wc + ni * 16 + l16;
        float bias = bp[n];
#pragma unroll
        for (int mi = 0; mi < 4; ++mi)
#pragma unroll
            for (int r = 0; r < 4; ++r) {
                int m = m0 + wr + mi * 16 + quad * 4 + r;
                out[(size_t)m * 1024 + n] = acc[mi][ni][r] + bias;
            }
    }
}

// ---------------- flash attention (causal), 32x32 swapped-QK^T, SPLIT-K ----------------
// Block = 8 waves (512 thr), one head. Wave w: q-tile tq = 4t + (w&3),
// key parity p = w>>2 -> processes kt === p (mod 2), kt <= ktmax = tq>>1.
// Per barrier: stage TWO 64-key tiles (parities 0,1 of the stage). Images
// swizzled phys_chunk = logical ^ (row&7); reads XOR by l31&7.
// Per active sub-tile: S^T = mfma32(K,Q^T); exp2 (lane-local l, treed sum);
// P^T repack via v_permlane32_swap_b32; O^T += mfma32(V^T, P^T).
// End: parity-1 waves write (O^T,l) to LDS; parity-0 add (exact: no running
// max in this softmax), then O^T -> O transpose via LDS, coalesced stores.

#define STAGE128(KT2, B) do {                                                 \
    const u16* kt_ = Kh + (size_t)(KT2) * 8192;                               \
    const u16* vt_ = Vh + (size_t)(KT2) * 8192;                               \
    _Pragma("unroll") for (int i_ = 0; i_ < 2; ++i_) {                        \
        int ci_ = i_ * 512 + tid;            /* 0..1023: 128 rows x 8 chks */ \
        gload_lds16(kt_ + (ci_ >> 3) * 64 +                                   \
                    (((ci_ & 7) ^ ((ci_ >> 3) & 7)) * 8),                     \
                    SMEM[B][0] + ci_ * 8);                                    \
        gload_lds16(vt_ + (ci_ >> 3) * 64 +                                   \
                    (((ci_ & 7) ^ ((ci_ >> 3) & 7)) * 8),                     \
                    SMEM[B][1] + ci_ * 8);                                    \
    }                                                                         \
} while (0)

// one PV k-slice SG (keys 16*SG..+15 of the sub-tile); BFR = P^T frag (4 u32)
#define PVSTEP(SG, BFR) do {                                                  \
    bf8 va_ = *(const bf8*)(vb_ + l31 * 64 + (((2 * (SG) + h) ^ swz) * 8));   \
    bf8 vc_ = *(const bf8*)(vb_ + (32 + l31) * 64 +                           \
                            (((2 * (SG) + h) ^ swz) * 8));                    \
    bf8 pf_ = __builtin_bit_cast(bf8, BFR);                                   \
    oT0 = mfma32(va_, pf_, oT0);                                              \
    oT1 = mfma32(vc_, pf_, oT1);                                              \
} while (0)

// pack 32 S^T values -> 8 u32, exchange halves via permlane32_swap: the two
// outputs of each swap are exactly the two B-frag words (R16 BFRAGS mapping).
#define REPACK_PV(ST, SG0, SG1) do {                                          \
    u32 pk_[8];                                                               \
    _Pragma("unroll") for (int j = 0; j < 8; ++j)                             \
        pk_[j] = pk2(ST[2 * j], ST[2 * j + 1]);                               \
    pl32swap(pk_[0], pk_[2]); pl32swap(pk_[1], pk_[3]);                       \
    pl32swap(pk_[4], pk_[6]); pl32swap(pk_[5], pk_[7]);                       \
    u32x4v f0_ = {pk_[0], pk_[1], pk_[2], pk_[3]};                            \
    u32x4v f1_ = {pk_[4], pk_[5], pk_[6], pk_[7]};                            \
    PVSTEP(SG0, f0_);                                                         \
    PVSTEP(SG1, f1_);                                                         \
} while (0)

// balanced tree sum of 16 floats (no 16-deep serial chain)
#define TREE16(S)                                                             \
    (((((S)[0] + (S)[1]) + ((S)[2] + (S)[3])) +                               \
      (((S)[4] + (S)[5]) + ((S)[6] + (S)[7]))) +                              \
     ((((S)[8] + (S)[9]) + ((S)[10] + (S)[11])) +                             \
      (((S)[12] + (S)[13]) + ((S)[14] + (S)[15]))))

__global__ __launch_bounds__(512, 4) void k_attn(const u16* __restrict__ Qb,
                                                 const u16* __restrict__ Kb,
                                                 const u16* __restrict__ Vtb,
                                                 u16* __restrict__ AO) {
    // 512 blocks; same-head blocks share id%8 (XCD L2 affinity). Longest first.
    int id = blockIdx.x;                     // 0..511
    int bh = (id & 7) * 4 + ((id >> 3) & 3); // head-batch 0..31
    int t  = 15 - (id >> 5);                 // 0..15
    int tid = threadIdx.x;                   // 0..511
    int w = tid >> 6, lane = tid & 63, l31 = lane & 31, h = lane >> 5;
    int wq = w & 3, p = w >> 2;              // q-slot, key parity

    const u16* Qh = Qb  + (size_t)bh * 131072;
    const u16* Kh = Kb  + (size_t)bh * 131072;
    const u16* Vh = Vtb + (size_t)bh * 131072;      // V^T tiled: [kt][d][t64]

    __shared__ u16 SMEM[2][2][8192];         // [buf][K|V][image] = 64KB

    int tq = 4 * t + wq;                     // q-tile; equal ktmax +-1
    int qr = tq * 32;
    int ktmax = tq >> 1;                     // wave's last 64-key tile
    int nk2 = t + 1;                         // block-uniform 128-key stages

    // Q^T fragments (B-operand): lane reads its own q-row, 4 d-slices.
    bf8 qf[4];
#pragma unroll
    for (int s = 0; s < 4; ++s)
        qf[s] = *(const bf8*)(Qh + (size_t)(qr + l31) * 64 + s * 16 + h * 8);

    float l_acc = 0.f;
    f32x16 oT0, oT1;
#pragma unroll
    for (int r = 0; r < 16; ++r) { oT0[r] = 0.f; oT1[r] = 0.f; }

    int swz = l31 & 7;                       // unified read-side XOR selector

    STAGE128(0, 0);
    for (int k2 = 0; k2 < nk2; ++k2) {
        int pb = k2 & 1;
        __syncthreads();                     // drains buf[pb] staging
        if (k2 + 1 < nk2) STAGE128(k2 + 1, pb ^ 1);

        int kt = 2 * k2 + p;                 // this wave's parity sub-tile
        if (kt <= ktmax) {                   // wave-uniform
            const u16* kb_ = SMEM[pb][0] + p * 4096;
            const u16* vb_ = SMEM[pb][1] + p * 4096;
            bool diag = (kt == ktmax);
            bool doK1 = !(diag && ((tq & 1) == 0));

            // ---- QK^T: S^T = K · Q^T ----
            f32x16 sT0, sT1;
#pragma unroll
            for (int r = 0; r < 16; ++r) { sT0[r] = 0.f; sT1[r] = 0.f; }
#pragma unroll
            for (int d = 0; d < 4; ++d) {
                bf8 kf = *(const bf8*)(kb_ + l31 * 64 +
                                       (((2 * d + h) ^ swz) * 8));
                sT0 = mfma32(kf, qf[d], sT0);
            }
            if (doK1) {
#pragma unroll
                for (int d = 0; d < 4; ++d) {
                    bf8 kf = *(const bf8*)(kb_ + (32 + l31) * 64 +
                                           (((2 * d + h) ^ swz) * 8));
                    sT1 = mfma32(kf, qf[d], sT1);
                }
            }

            // ---- softmax (exp2, Q pre-scaled; mask only on diag tile) ----
            int kb0 = kt * 64, qg = qr + l31;
            if (diag) {
#pragma unroll
                for (int r = 0; r < 16; ++r) {
                    int krow = kb0 + (r & 3) + 8 * (r >> 2) + 4 * h;
                    sT0[r] = fexp2(krow <= qg ? sT0[r] : -1e30f);
                }
                if (doK1) {
#pragma unroll
                    for (int r = 0; r < 16; ++r) {
                        int krow = kb0 + 32 + (r & 3) + 8 * (r >> 2) + 4 * h;
                        sT1[r] = fexp2(krow <= qg ? sT1[r] : -1e30f);
                    }
                }
            } else {
#pragma unroll
                for (int r = 0; r < 16; ++r) sT0[r] = fexp2(sT0[r]);
#pragma unroll
                for (int r = 0; r < 16; ++r) sT1[r] = fexp2(sT1[r]);
            }
            l_acc += TREE16(sT0);
            if (doK1) l_acc += TREE16(sT1);

            // ---- P^T repack (permlane32_swap) + PV ----
            REPACK_PV(sT0, 0, 1);
            if (doK1) REPACK_PV(sT1, 2, 3);
        }
    }

    // ---- split-K combine: parity-1 -> LDS, parity-0 adds (exact) ----
    __syncthreads();                         // all KV reads done
    float* comb = (float*)&SMEM[0][0][0];    // 4*64*36 floats = 36KB
    if (p == 1) {
        float* cw = comb + (wq * 64 + lane) * 36;   // 144B stride, 16B-aligned
#pragma unroll
        for (int r = 0; r < 16; ++r) { cw[r] = oT0[r]; cw[16 + r] = oT1[r]; }
        cw[32] = l_acc;
    }
    __syncthreads();
    if (p == 1) return;                      // no barriers below

    const float* cr = comb + (wq * 64 + lane) * 36;
#pragma unroll
    for (int r = 0; r < 16; ++r) { oT0[r] += cr[r]; oT1[r] += cr[16 + r]; }
    l_acc += cr[32];

    float lsum = l_acc + __shfl_xor(l_acc, 32, 64);
    float linv = __builtin_amdgcn_rcpf(lsum);

    // ---- epilogue: normalize, transpose O^T -> O via LDS (disjoint region) ----
    u32* Ot = (u32*)&SMEM[0][0][0] + 9216 + wq * 1152;   // [32 q][36-pad u32]
#pragma unroll
    for (int j = 0; j < 8; ++j) {
        int col = 4 * (j >> 1) + 2 * h + (j & 1);   // d/2 within 32-block
        Ot[l31 * 36 + col]      = pk2(oT0[2 * j] * linv, oT0[2 * j + 1] * linv);
        Ot[l31 * 36 + 16 + col] = pk2(oT1[2 * j] * linv, oT1[2 * j + 1] * linv);
    }
    asm volatile("s_waitcnt lgkmcnt(0)" ::: "memory");
    __builtin_amdgcn_sched_barrier(0);       // rule #18: pin reads after fence

    int q2 = lane >> 1, half = lane & 1;
    int eb = bh >> 4, eh = bh & 15;
    size_t row = (size_t)eb * 2048 + qr + q2;
    const u32* src = Ot + q2 * 36 + half * 16;
    u32* dstg = (u32*)(AO + row * 1024 + eh * 64) + half * 16;
#pragma unroll
    for (int c = 0; c < 4; ++c)
        *(u32x4v*)(dstg + 4 * c) = *(const u32x4v*)(src + 4 * c);
}

extern "C" void kernel_launch(void* const* d_in, const int* in_sizes, int n_in,
                              void* d_out, int out_size, void* d_ws, size_t ws_size,
                              hipStream_t stream) {
    const float* x  = (const float*)d_in[0];
    const float* Wa = (const float*)d_in[1];
    const float* ba = (const float*)d_in[2];
    const float* Wp = (const float*)d_in[3];
    const float* bp = (const float*)d_in[4];
    float* out = (float*)d_out;

    char* ws = (char*)d_ws;
    const size_t MB = 1024 * 1024;
    u16* Xb  = (u16*)(ws);             // 8 MB  x as bf16   (reused as AO later)
    u16* WtA = (u16*)(ws + 8  * MB);   // 6 MB  W_attn^T bf16
    u16* WtP = (u16*)(ws + 14 * MB);   // 2 MB  W_proj^T bf16
    u16* Qb  = (u16*)(ws + 16 * MB);   // 8 MB  [B*H][T][D], pre-scaled
    u16* Kb  = (u16*)(ws + 24 * MB);   // 8 MB  [B*H][T][D]
    u16* Vtb = (u16*)(ws + 32 * MB);   // 8 MB  [B*H][32][64][64] tiled V^T
    u16* AO  = Xb;                     // alias: Xb dead after k_qkv (stream-ordered)

    k_prep<<<dim3(5120),    dim3(256), 0, stream>>>(x, Wa, Wp, Xb, WtA, WtP);
    k_qkv <<<dim3(32, 24),  dim3(256), 0, stream>>>(Xb, WtA, ba, Qb, Kb, Vtb);
    k_attn<<<dim3(512),     dim3(512), 0, stream>>>(Qb, Kb, Vtb, AO);
    k_proj<<<dim3(32, 8),   dim3(256), 0, stream>>>(AO, WtP, bp, out);
}